// Round 16
// baseline (173.510 us; speedup 1.0000x reference)
//
#include <hip/hip_runtime.h>
#include <hip/hip_bf16.h>

// Linformer MHA, MI355X gfx950. Round 16: counted-vmcnt dual-barrier schedule
// (T4) in gemmT AND attn — prefetch loads stay in flight across barriers
// (no vmcnt(0) drain). gemmT: LDS dbuf + vmcnt(6). attn: QBLK=128 (R14
// structure, best), prescaled-Q exp2, vmcnt(2).
// Pipeline (stream-ordered aliasing, ws = 32MB exactly):
//   k_convert_a: q,k,v -> Xqb[0:4M) Xkb[4M:8M) Xvb[8M:12M); Wq/Wk/Wv/Wo -> [12M:16M)
//   k_kv   : K/V projections -> KbT/VbT in d_out
//   k_q    : Q projection (masked, pre-scaled by 0.125*log2e) -> Qb @ [4M:8M)
//   k_convert_b: WkP/WvP -> [8M:12M)
//   k_linproj: -> Kp[0:2M) VpT[2M:4M)
//   attn   : -> Xo[8M:12M)
//   k_outproj: -> fp32 d_out

typedef __attribute__((ext_vector_type(4))) float  f32x4;
typedef __attribute__((ext_vector_type(8))) short  short8;
typedef __attribute__((ext_vector_type(4))) short  short4_t;
typedef __attribute__((ext_vector_type(2))) unsigned int uint32x2;
typedef __attribute__((ext_vector_type(8))) __bf16 bf16x8;
typedef unsigned short ushort_t;

#define DEV __device__ __forceinline__

constexpr int B_ = 2, S_ = 2048, D_ = 1024, H_ = 16, SP_ = 1024;
constexpr size_t M1 = 1u << 20;
constexpr size_t XQ_OFF = 0,      XK_OFF = 4*M1,  XV_OFF = 8*M1,
                 WQ_OFF = 12*M1,  WK_OFF = 13*M1, WV_OFF = 14*M1, WO_OFF = 15*M1,
                 QB_OFF = 4*M1,   KP_OFF = 0,     VPT_OFF = 2*M1,
                 WKPB_OFF = 8*M1, WVPB_OFF = 10*M1, XO_OFF = 8*M1;
constexpr float CSC = 0.18033688011112042f;   // 0.125 * log2(e)

DEV ushort_t f2bf(float f) {              // RNE fp32 -> bf16 bits
  unsigned u = __builtin_bit_cast(unsigned, f);
  unsigned r = ((u >> 16) & 1u) + 0x7FFFu;
  return (ushort_t)((u + r) >> 16);
}
DEV bf16x8 ld8(const ushort_t* p) {
  return __builtin_bit_cast(bf16x8, *reinterpret_cast<const short8*>(p));
}
DEV f32x4 mfma16(bf16x8 a, bf16x8 b, f32x4 c) {
  return __builtin_amdgcn_mfma_f32_16x16x32_bf16(a, b, c, 0, 0, 0);
}
DEV void gload16(const ushort_t* g, ushort_t* l) {   // 16B global -> LDS direct
  __builtin_amdgcn_global_load_lds(
      (const __attribute__((address_space(1))) void*)g,
      (__attribute__((address_space(3))) void*)l, 16, 0, 0);
}
DEV void cvt2048(const float* src, ushort_t* dst, int tid) {
  const size_t off = (size_t)tid * 8;
  float4 f0 = *reinterpret_cast<const float4*>(src + off);
  float4 f1 = *reinterpret_cast<const float4*>(src + off + 4);
  ushort_t t[8] = { f2bf(f0.x), f2bf(f0.y), f2bf(f0.z), f2bf(f0.w),
                    f2bf(f1.x), f2bf(f1.y), f2bf(f1.z), f2bf(f1.w) };
  *reinterpret_cast<short8*>(dst + off) = *reinterpret_cast<short8*>(t);
}

// ---------------------------------------------------------------------------
// Conversion A: q,k,v (12M) + Wq,Wk,Wv,Wo (4M) -> bf16. 8192 blocks x 2048 el.
// ---------------------------------------------------------------------------
__global__ __launch_bounds__(256) void k_convert_a(
    const float* __restrict__ q, const float* __restrict__ k,
    const float* __restrict__ v, const float* __restrict__ Wq,
    const float* __restrict__ Wk, const float* __restrict__ Wv,
    const float* __restrict__ Wo, ushort_t* __restrict__ ws)
{
  int blk = blockIdx.x; const float* src; ushort_t* dst;
  if      (blk < 2048) { src = q;  dst = ws + XQ_OFF; }
  else if (blk < 4096) { src = k;  dst = ws + XK_OFF; blk -= 2048; }
  else if (blk < 6144) { src = v;  dst = ws + XV_OFF; blk -= 4096; }
  else if (blk < 6656) { src = Wq; dst = ws + WQ_OFF; blk -= 6144; }
  else if (blk < 7168) { src = Wk; dst = ws + WK_OFF; blk -= 6656; }
  else if (blk < 7680) { src = Wv; dst = ws + WV_OFF; blk -= 7168; }
  else                 { src = Wo; dst = ws + WO_OFF; blk -= 7680; }
  cvt2048(src + (size_t)blk * 2048, dst + (size_t)blk * 2048, threadIdx.x);
}

// Conversion B: WkP, WvP (4M elems) -> bf16. 2048 blocks.
__global__ __launch_bounds__(256) void k_convert_b(
    const float* __restrict__ WkP, const float* __restrict__ WvP,
    ushort_t* __restrict__ ws)
{
  int blk = blockIdx.x; const float* src; ushort_t* dst;
  if (blk < 1024) { src = WkP; dst = ws + WKPB_OFF; }
  else            { src = WvP; dst = ws + WVPB_OFF; blk -= 1024; }
  cvt2048(src + (size_t)blk * 2048, dst + (size_t)blk * 2048, threadIdx.x);
}

// ---------------------------------------------------------------------------
// 64x128xK bf16 MFMA GEMM, 256 thr (4 waves), BK=64, LDS DOUBLE-buffered,
// counted-vmcnt dual-barrier K-loop: stage(next 6 loads) -> vmcnt(6) ->
// s_barrier -> compute(cur) -> s_barrier. Next tile's loads stay in flight
// across both barriers (no vmcnt(0) drain). 128B rows XOR-swizzled.
// EPI: 0 none, 1 mask-row, 2 exact-GELU, 3 mask-row + scale-by-CSC.
// OUTMODE: 0 bf16 C[m][n]; 1 fp32 C[m][n]; 2 bf16 Ct[b][n][s]; 3 bf16 Ct[n][m].
// ---------------------------------------------------------------------------
template<int BIAS, int EPI, int OUTMODE>
DEV void gemmT(const ushort_t* Ap, const ushort_t* Bp, const float* bias,
               const int* mask, void* Cp, int M, int N, int K)
{
  __shared__ __align__(16) ushort_t As[2][64 * 64];    // 16KB
  __shared__ __align__(16) ushort_t Bs[2][128 * 64];   // 32KB
  const int tid = threadIdx.x;

  const int gx = gridDim.x, gy = gridDim.y, nwg = gx * gy;
  int lin = blockIdx.y * gx + blockIdx.x;
  lin = (lin & 7) * (nwg >> 3) + (lin >> 3);
  const int m0 = (lin / gy) * 64, n0 = (lin % gy) * 128;

  const int w = tid >> 6, lane = tid & 63, lr = lane & 15, lg = lane >> 4;
  const int wm = (w >> 1) * 32, wn = (w & 1) * 64;
  const int rk7 = lr & 7;

  f32x4 acc[2][4];
#pragma unroll
  for (int i = 0; i < 2; ++i)
#pragma unroll
    for (int j = 0; j < 4; ++j) acc[i][j] = f32x4{0.f, 0.f, 0.f, 0.f};

  const int srow = tid >> 3;                          // 0..31
  const int schx = ((tid & 7) ^ (srow & 7)) * 8;      // pre-swizzled col off
  const ushort_t* Ag = Ap + (size_t)(m0 + srow) * K + schx;
  const ushort_t* Bg = Bp + (size_t)(n0 + srow) * K + schx;

  auto stage = [&](int buf, int k0) {
    gload16(Ag + k0,                 As[buf] + tid*8);
    gload16(Ag + (size_t)32*K + k0,  As[buf] + 2048 + tid*8);
    gload16(Bg + k0,                 Bs[buf] + tid*8);
    gload16(Bg + (size_t)32*K + k0,  Bs[buf] + 2048 + tid*8);
    gload16(Bg + (size_t)64*K + k0,  Bs[buf] + 4096 + tid*8);
    gload16(Bg + (size_t)96*K + k0,  Bs[buf] + 6144 + tid*8);
  };

  stage(0, 0);
  int cur = 0;
  for (int k0 = 0; k0 < K; k0 += 64) {
    if (k0 + 64 < K) {
      stage(cur ^ 1, k0 + 64);
      asm volatile("s_waitcnt vmcnt(6)" ::: "memory");   // cur's 6 loads done
    } else {
      asm volatile("s_waitcnt vmcnt(0)" ::: "memory");
    }
    __builtin_amdgcn_s_barrier();            // all waves: cur buffer ready
    __builtin_amdgcn_sched_barrier(0);

#pragma unroll
    for (int ks = 0; ks < 2; ++ks) {
      bf16x8 af[2], bfv[4];
#pragma unroll
      for (int i = 0; i < 2; ++i)
        af[i]  = ld8(&As[cur][(wm + i*16 + lr)*64 + (((ks<<2)|lg) ^ rk7)*8]);
#pragma unroll
      for (int j = 0; j < 4; ++j)
        bfv[j] = ld8(&Bs[cur][(wn + j*16 + lr)*64 + (((ks<<2)|lg) ^ rk7)*8]);
#pragma unroll
      for (int i = 0; i < 2; ++i)
#pragma unroll
        for (int j = 0; j < 4; ++j)
          acc[i][j] = mfma16(af[i], bfv[j], acc[i][j]);
    }

    __builtin_amdgcn_sched_barrier(0);
    __builtin_amdgcn_s_barrier();            // all waves done reading cur
    cur ^= 1;
  }

#pragma unroll
  for (int i = 0; i < 2; ++i) {
    const int mBase = m0 + wm + i*16 + 4*lg;
#pragma unroll
    for (int j = 0; j < 4; ++j) {
      const int n = n0 + wn + j*16 + lr;
      float vv[4];
#pragma unroll
      for (int r = 0; r < 4; ++r) {
        const int m = mBase + r;
        float v = acc[i][j][r];
        if (BIAS == 2) v += bias[n];
        if (BIAS == 1) v += bias[m];
        if (EPI == 1 || EPI == 3) v = mask[m] ? v : 0.f;
        if (EPI == 3)  v *= CSC;
        if (EPI == 2)  v = 0.5f * v * (1.f + erff(v * 0.70710678118654752f));
        vv[r] = v;
      }
      if (OUTMODE == 0) {
#pragma unroll
        for (int r = 0; r < 4; ++r)
          ((ushort_t*)Cp)[(size_t)(mBase + r) * N + n] = f2bf(vv[r]);
      } else if (OUTMODE == 1) {
#pragma unroll
        for (int r = 0; r < 4; ++r)
          ((float*)Cp)[(size_t)(mBase + r) * N + n] = vv[r];
      } else if (OUTMODE == 2) {       // Ct[b][n][s], s=m-b*S_ (K/V proj path)
        const int bb = mBase >> 11;
        const int sb = mBase & (S_ - 1);
        ushort_t t4[4] = { f2bf(vv[0]), f2bf(vv[1]), f2bf(vv[2]), f2bf(vv[3]) };
        *reinterpret_cast<short4_t*>(
            (ushort_t*)Cp + ((size_t)bb * D_ + n) * S_ + sb) =
            *reinterpret_cast<short4_t*>(t4);
      } else {                         // Ct[n][m], stride M (linproj V path)
        ushort_t t4[4] = { f2bf(vv[0]), f2bf(vv[1]), f2bf(vv[2]), f2bf(vv[3]) };
        *reinterpret_cast<short4_t*>(
            (ushort_t*)Cp + (size_t)n * M + mBase) =
            *reinterpret_cast<short4_t*>(t4);
      }
    }
  }
}

// --------------------------- kernel wrappers -------------------------------
__global__ __launch_bounds__(256) void k_kv(
    const float* __restrict__ bk, const float* __restrict__ bv,
    const int* __restrict__ mask, const ushort_t* __restrict__ ws,
    ushort_t* __restrict__ KbT, ushort_t* __restrict__ VbT)
{
  if (blockIdx.z == 0)
    gemmT<2, 1, 2>(ws + XK_OFF, ws + WK_OFF, bk, mask, KbT, B_*S_, D_, D_);
  else
    gemmT<2, 1, 2>(ws + XV_OFF, ws + WV_OFF, bv, mask, VbT, B_*S_, D_, D_);
}

__global__ __launch_bounds__(256) void k_q(
    const float* __restrict__ bq, const int* __restrict__ mask,
    const ushort_t* __restrict__ ws, ushort_t* __restrict__ Qb)
{
  gemmT<2, 3, 0>(ws + XQ_OFF, ws + WQ_OFF, bq, mask, Qb, B_*S_, D_, D_);
}

__global__ __launch_bounds__(256) void k_linproj(
    const float* __restrict__ bkP, const float* __restrict__ bvP,
    const ushort_t* __restrict__ ws, const ushort_t* __restrict__ KbT,
    const ushort_t* __restrict__ VbT, ushort_t* __restrict__ Kp,
    ushort_t* __restrict__ VpT)
{
  const int z = blockIdx.z, b = z >> 1, isv = z & 1;
  if (isv) {
    gemmT<1, 2, 3>(ws + WVPB_OFF, VbT + (size_t)b * D_ * S_, bvP,
                   nullptr, VpT + (size_t)b * D_ * SP_, SP_, D_, S_);
  } else {
    gemmT<1, 2, 0>(ws + WKPB_OFF, KbT + (size_t)b * D_ * S_, bkP,
                   nullptr, Kp + (size_t)b * SP_ * D_, SP_, D_, S_);
  }
}

__global__ __launch_bounds__(256) void k_outproj(
    const ushort_t* __restrict__ Xo, const ushort_t* __restrict__ Wob,
    const float* __restrict__ bo, float* __restrict__ out)
{
  gemmT<2, 0, 1>(Xo, Wob, bo, nullptr, out, B_*S_, D_, D_);
}

// ---------------------------------------------------------------------------
// Fused attention v8: 512 thr, QBLK=128 (R14 best), KVBLK=64, LDS-staged
// K/V^T (gload, dbuf, XOR swizzle), counted-vmcnt dual-barrier loop
// (vmcnt(2), no drain), swapped QK^T + cvt_pk P-pack, prescaled-Q exp2,
// per-lane scalar denominator.
// ---------------------------------------------------------------------------
__global__ __launch_bounds__(512) void attn_kernel(
    const ushort_t* __restrict__ Qb, const ushort_t* __restrict__ Kp,
    const ushort_t* __restrict__ VpT, ushort_t* __restrict__ Xo)
{
  __shared__ __align__(16) ushort_t Ks[2][64 * 64];
  __shared__ __align__(16) ushort_t Vs[2][64 * 64];
  __shared__ __align__(16) ushort_t Pl[8][16][72];   // per-wave P [q][p+pad]

  const int b = blockIdx.z, h = blockIdx.y, s0 = blockIdx.x * 128;
  const int tid = threadIdx.x, w = tid >> 6, lane = tid & 63;
  const int lr = lane & 15, lg = lane >> 4;

  const ushort_t* qp = Qb + (size_t)(b * S_ + s0 + w*16 + lr) * D_ + h * 64;
  const bf16x8 aq0 = ld8(qp + 8*lg);        // d = 0..31 slice (pre-scaled)
  const bf16x8 aq1 = ld8(qp + 32 + 8*lg);   // d = 32..63 slice

  const ushort_t* kbase = Kp  + (size_t)b * SP_ * D_ + h * 64;
  const ushort_t* vbase = VpT + (size_t)b * D_ * SP_ + (size_t)(h*64) * SP_;

  const int srow = tid >> 3, sch = tid & 7;
  const int schx = (sch ^ (srow & 7)) << 3;
  const int rk7 = lr & 7;

  f32x4 o[4];
#pragma unroll
  for (int dt = 0; dt < 4; ++dt) o[dt] = f32x4{0.f, 0.f, 0.f, 0.f};
  float lsum4[4] = {0.f, 0.f, 0.f, 0.f};    // per-lane (q=lr) partial denoms

  auto stage = [&](int buf, int p0) {
    gload16(kbase + (size_t)(p0 + srow) * D_ + schx, Ks[buf] + tid*8);
    gload16(vbase + (size_t)srow * SP_ + p0 + schx,  Vs[buf] + tid*8);
  };

  stage(0, 0);
  int cur = 0;
  for (int pt = 0; pt < SP_ / 64; ++pt) {
    if (pt + 1 < SP_ / 64) {
      stage(cur ^ 1, (pt + 1) * 64);
      asm volatile("s_waitcnt vmcnt(2)" ::: "memory");  // cur's 2 loads done
    } else {
      asm volatile("s_waitcnt vmcnt(0)" ::: "memory");
    }
    __builtin_amdgcn_s_barrier();
    __builtin_amdgcn_sched_barrier(0);

    // ---- S^T = K Q^T (swapped); P = exp2(S^T); pack + 1 b64 write/nt ----
#pragma unroll
    for (int nt = 0; nt < 4; ++nt) {
      const ushort_t* krow = Ks[cur] + (nt*16 + lr) * 64;
      f32x4 a = f32x4{0.f, 0.f, 0.f, 0.f};
      a = mfma16(ld8(krow + ((lg       ^ rk7) << 3)), aq0, a);
      a = mfma16(ld8(krow + (((4 + lg) ^ rk7) << 3)), aq1, a);
      const float e0 = __builtin_exp2f(a[0]);
      const float e1 = __builtin_exp2f(a[1]);
      const float e2 = __builtin_exp2f(a[2]);
      const float e3 = __builtin_exp2f(a[3]);
      lsum4[nt] += (e0 + e1) + (e2 + e3);
      unsigned p01, p23;
      asm("v_cvt_pk_bf16_f32 %0, %1, %2" : "=v"(p01) : "v"(e0), "v"(e1));
      asm("v_cvt_pk_bf16_f32 %0, %1, %2" : "=v"(p23) : "v"(e2), "v"(e3));
      uint32x2 pw; pw[0] = p01; pw[1] = p23;
      *reinterpret_cast<uint32x2*>(&Pl[w][lr][nt*16 + 4*lg]) = pw;
    }

    // ---- O += P @ V ----
    const bf16x8 pa0 = ld8(&Pl[w][lr][8*lg]);        // p = 0..31 slice
    const bf16x8 pa1 = ld8(&Pl[w][lr][32 + 8*lg]);   // p = 32..63 slice
#pragma unroll
    for (int dt = 0; dt < 4; ++dt) {
      const ushort_t* vrow = Vs[cur] + (dt*16 + lr) * 64;
      o[dt] = mfma16(pa0, ld8(vrow + ((lg       ^ rk7) << 3)), o[dt]);
      o[dt] = mfma16(pa1, ld8(vrow + (((4 + lg) ^ rk7) << 3)), o[dt]);
    }

    __builtin_amdgcn_sched_barrier(0);
    __builtin_amdgcn_s_barrier();
    cur ^= 1;
  }

  // ---- denominator: reduce 4 lane-groups (same q=lr), then broadcast ----
  float lsum = (lsum4[0] + lsum4[1]) + (lsum4[2] + lsum4[3]);
  lsum += __shfl_xor(lsum, 16, 64);
  lsum += __shfl_xor(lsum, 32, 64);          // every lane: total for q=lr
  float linv[4];
#pragma unroll
  for (int r = 0; r < 4; ++r)
    linv[r] = 1.f / __shfl(lsum, 4*lg + r, 64);   // lane (4lg+r) has q=4lg+r

#pragma unroll
  for (int dt = 0; dt < 4; ++dt)
#pragma unroll
    for (int r = 0; r < 4; ++r) {
      const int srow2 = s0 + w*16 + 4*lg + r;
      Xo[(size_t)(b * S_ + srow2) * D_ + h*64 + dt*16 + lr] =
          f2bf(o[dt][r] * linv[r]);
    }
}

// ------------------------------- launch ------------------------------------
extern "C" void kernel_launch(void* const* d_in, const int* in_sizes, int n_in,
                              void* d_out, int out_size, void* d_ws, size_t ws_size,
                              hipStream_t stream)
{
  const float* q   = (const float*)d_in[0];
  const float* k   = (const float*)d_in[1];
  const float* v   = (const float*)d_in[2];
  const int*   msk = (const int*)d_in[3];
  const float* Wq  = (const float*)d_in[4];
  const float* bq  = (const float*)d_in[5];
  const float* Wk  = (const float*)d_in[6];
  const float* bk  = (const float*)d_in[7];
  const float* Wv  = (const float*)d_in[8];
  const float* bv  = (const float*)d_in[9];
  const float* Wo  = (const float*)d_in[10];
  const float* bo  = (const float*)d_in[11];
  const float* WkP = (const float*)d_in[12];
  const float* bkP = (const float*)d_in[13];
  const float* WvP = (const float*)d_in[14];
  const float* bvP = (const float*)d_in[15];

  ushort_t* ws  = (ushort_t*)d_ws;
  ushort_t* Qb  = ws + QB_OFF;
  ushort_t* Kp  = ws + KP_OFF;
  ushort_t* VpT = ws + VPT_OFF;
  ushort_t* Xo  = ws + XO_OFF;
  ushort_t* KbT = (ushort_t*)d_out;     // d_out as scratch until k_outproj
  ushort_t* VbT = KbT + 4 * M1;

  dim3 blk(256, 1, 1);
  k_convert_a<<<dim3(8192, 1, 1), blk, 0, stream>>>(q, k, v, Wq, Wk, Wv, Wo, ws);
  k_kv     <<<dim3(B_*S_/64, D_/128, 2), blk, 0, stream>>>(bk, bv, msk, ws, KbT, VbT);
  k_q      <<<dim3(B_*S_/64, D_/128, 1), blk, 0, stream>>>(bq, msk, ws, Qb);
  k_convert_b<<<dim3(2048, 1, 1), blk, 0, stream>>>(WkP, WvP, ws);
  k_linproj<<<dim3(SP_/64,  D_/128, 4), blk, 0, stream>>>(bkP, bvP, ws, KbT, VbT, Kp, VpT);
  attn_kernel<<<dim3(S_/128, H_, B_), dim3(512,1,1), 0, stream>>>(Qb, Kp, VpT, Xo);
  k_outproj<<<dim3(B_*S_/64, D_/128, 1), blk, 0, stream>>>(Xo, ws + WO_OFF, bo, (float*)d_out);
}

// Round 17
// 154.474 us; speedup vs baseline: 1.1232x; 1.1232x over previous
//
#include <hip/hip_runtime.h>
#include <hip/hip_bf16.h>

// Linformer MHA, MI355X gfx950. Round 17: round-16 counted-vmcnt schedule with
// the LDS-duplication bug fixed — shared buffers hoisted to kernel scope and
// passed into gemmT (one 48KB allocation per kernel; round 16's two template
// instantiations each carried their own static __shared__ -> 96KB -> 1 blk/CU).
// Pipeline (stream-ordered aliasing, ws = 32MB exactly):
//   k_convert_a: q,k,v -> Xqb[0:4M) Xkb[4M:8M) Xvb[8M:12M); Wq/Wk/Wv/Wo -> [12M:16M)
//   k_kv   : K/V projections -> KbT/VbT in d_out
//   k_q    : Q projection (masked, pre-scaled by 0.125*log2e) -> Qb @ [4M:8M)
//   k_convert_b: WkP/WvP -> [8M:12M)
//   k_linproj: -> Kp[0:2M) VpT[2M:4M)
//   attn   : -> Xo[8M:12M)
//   k_outproj: -> fp32 d_out

typedef __attribute__((ext_vector_type(4))) float  f32x4;
typedef __attribute__((ext_vector_type(8))) short  short8;
typedef __attribute__((ext_vector_type(4))) short  short4_t;
typedef __attribute__((ext_vector_type(2))) unsigned int uint32x2;
typedef __attribute__((ext_vector_type(8))) __bf16 bf16x8;
typedef unsigned short ushort_t;

#define DEV __device__ __forceinline__

constexpr int B_ = 2, S_ = 2048, D_ = 1024, H_ = 16, SP_ = 1024;
constexpr size_t M1 = 1u << 20;
constexpr size_t XQ_OFF = 0,      XK_OFF = 4*M1,  XV_OFF = 8*M1,
                 WQ_OFF = 12*M1,  WK_OFF = 13*M1, WV_OFF = 14*M1, WO_OFF = 15*M1,
                 QB_OFF = 4*M1,   KP_OFF = 0,     VPT_OFF = 2*M1,
                 WKPB_OFF = 8*M1, WVPB_OFF = 10*M1, XO_OFF = 8*M1;
constexpr float CSC = 0.18033688011112042f;   // 0.125 * log2(e)

DEV ushort_t f2bf(float f) {              // RNE fp32 -> bf16 bits
  unsigned u = __builtin_bit_cast(unsigned, f);
  unsigned r = ((u >> 16) & 1u) + 0x7FFFu;
  return (ushort_t)((u + r) >> 16);
}
DEV bf16x8 ld8(const ushort_t* p) {
  return __builtin_bit_cast(bf16x8, *reinterpret_cast<const short8*>(p));
}
DEV f32x4 mfma16(bf16x8 a, bf16x8 b, f32x4 c) {
  return __builtin_amdgcn_mfma_f32_16x16x32_bf16(a, b, c, 0, 0, 0);
}
DEV void gload16(const ushort_t* g, ushort_t* l) {   // 16B global -> LDS direct
  __builtin_amdgcn_global_load_lds(
      (const __attribute__((address_space(1))) void*)g,
      (__attribute__((address_space(3))) void*)l, 16, 0, 0);
}
DEV void cvt2048(const float* src, ushort_t* dst, int tid) {
  const size_t off = (size_t)tid * 8;
  float4 f0 = *reinterpret_cast<const float4*>(src + off);
  float4 f1 = *reinterpret_cast<const float4*>(src + off + 4);
  ushort_t t[8] = { f2bf(f0.x), f2bf(f0.y), f2bf(f0.z), f2bf(f0.w),
                    f2bf(f1.x), f2bf(f1.y), f2bf(f1.z), f2bf(f1.w) };
  *reinterpret_cast<short8*>(dst + off) = *reinterpret_cast<short8*>(t);
}

// ---------------------------------------------------------------------------
// Conversion A: q,k,v (12M) + Wq,Wk,Wv,Wo (4M) -> bf16. 8192 blocks x 2048 el.
// ---------------------------------------------------------------------------
__global__ __launch_bounds__(256) void k_convert_a(
    const float* __restrict__ q, const float* __restrict__ k,
    const float* __restrict__ v, const float* __restrict__ Wq,
    const float* __restrict__ Wk, const float* __restrict__ Wv,
    const float* __restrict__ Wo, ushort_t* __restrict__ ws)
{
  int blk = blockIdx.x; const float* src; ushort_t* dst;
  if      (blk < 2048) { src = q;  dst = ws + XQ_OFF; }
  else if (blk < 4096) { src = k;  dst = ws + XK_OFF; blk -= 2048; }
  else if (blk < 6144) { src = v;  dst = ws + XV_OFF; blk -= 4096; }
  else if (blk < 6656) { src = Wq; dst = ws + WQ_OFF; blk -= 6144; }
  else if (blk < 7168) { src = Wk; dst = ws + WK_OFF; blk -= 6656; }
  else if (blk < 7680) { src = Wv; dst = ws + WV_OFF; blk -= 7168; }
  else                 { src = Wo; dst = ws + WO_OFF; blk -= 7680; }
  cvt2048(src + (size_t)blk * 2048, dst + (size_t)blk * 2048, threadIdx.x);
}

// Conversion B: WkP, WvP (4M elems) -> bf16. 2048 blocks.
__global__ __launch_bounds__(256) void k_convert_b(
    const float* __restrict__ WkP, const float* __restrict__ WvP,
    ushort_t* __restrict__ ws)
{
  int blk = blockIdx.x; const float* src; ushort_t* dst;
  if (blk < 1024) { src = WkP; dst = ws + WKPB_OFF; }
  else            { src = WvP; dst = ws + WVPB_OFF; blk -= 1024; }
  cvt2048(src + (size_t)blk * 2048, dst + (size_t)blk * 2048, threadIdx.x);
}

// ---------------------------------------------------------------------------
// 64x128xK bf16 MFMA GEMM, 256 thr (4 waves), BK=64, LDS double-buffered
// (buffers supplied by caller: As = [2][64*64], Bs = [2][128*64]).
// Counted-vmcnt dual-barrier K-loop: stage(next 6) -> vmcnt(6) -> s_barrier ->
// compute(cur) -> s_barrier. Prefetch stays in flight (no vmcnt(0) drain).
// 128B rows XOR-swizzled (pre-swizzled global src, swizzled ds_read).
// EPI: 0 none, 1 mask-row, 2 exact-GELU, 3 mask-row + scale-by-CSC.
// OUTMODE: 0 bf16 C[m][n]; 1 fp32 C[m][n]; 2 bf16 Ct[b][n][s]; 3 bf16 Ct[n][m].
// ---------------------------------------------------------------------------
template<int BIAS, int EPI, int OUTMODE>
DEV void gemmT(ushort_t* __restrict__ As, ushort_t* __restrict__ Bs,
               const ushort_t* Ap, const ushort_t* Bp, const float* bias,
               const int* mask, void* Cp, int M, int N, int K)
{
  const int tid = threadIdx.x;

  const int gx = gridDim.x, gy = gridDim.y, nwg = gx * gy;
  int lin = blockIdx.y * gx + blockIdx.x;
  lin = (lin & 7) * (nwg >> 3) + (lin >> 3);
  const int m0 = (lin / gy) * 64, n0 = (lin % gy) * 128;

  const int w = tid >> 6, lane = tid & 63, lr = lane & 15, lg = lane >> 4;
  const int wm = (w >> 1) * 32, wn = (w & 1) * 64;
  const int rk7 = lr & 7;

  f32x4 acc[2][4];
#pragma unroll
  for (int i = 0; i < 2; ++i)
#pragma unroll
    for (int j = 0; j < 4; ++j) acc[i][j] = f32x4{0.f, 0.f, 0.f, 0.f};

  const int srow = tid >> 3;                          // 0..31
  const int schx = ((tid & 7) ^ (srow & 7)) * 8;      // pre-swizzled col off
  const ushort_t* Ag = Ap + (size_t)(m0 + srow) * K + schx;
  const ushort_t* Bg = Bp + (size_t)(n0 + srow) * K + schx;

  auto stage = [&](int buf, int k0) {
    ushort_t* Ab = As + buf * 4096;
    ushort_t* Bb = Bs + buf * 8192;
    gload16(Ag + k0,                 Ab + tid*8);
    gload16(Ag + (size_t)32*K + k0,  Ab + 2048 + tid*8);
    gload16(Bg + k0,                 Bb + tid*8);
    gload16(Bg + (size_t)32*K + k0,  Bb + 2048 + tid*8);
    gload16(Bg + (size_t)64*K + k0,  Bb + 4096 + tid*8);
    gload16(Bg + (size_t)96*K + k0,  Bb + 6144 + tid*8);
  };

  stage(0, 0);
  int cur = 0;
  for (int k0 = 0; k0 < K; k0 += 64) {
    if (k0 + 64 < K) {
      stage(cur ^ 1, k0 + 64);
      asm volatile("s_waitcnt vmcnt(6)" ::: "memory");   // cur's 6 loads done
    } else {
      asm volatile("s_waitcnt vmcnt(0)" ::: "memory");
    }
    __builtin_amdgcn_s_barrier();            // all waves: cur buffer ready
    __builtin_amdgcn_sched_barrier(0);

    const ushort_t* Ac = As + cur * 4096;
    const ushort_t* Bc = Bs + cur * 8192;
#pragma unroll
    for (int ks = 0; ks < 2; ++ks) {
      bf16x8 af[2], bfv[4];
#pragma unroll
      for (int i = 0; i < 2; ++i)
        af[i]  = ld8(&Ac[(wm + i*16 + lr)*64 + (((ks<<2)|lg) ^ rk7)*8]);
#pragma unroll
      for (int j = 0; j < 4; ++j)
        bfv[j] = ld8(&Bc[(wn + j*16 + lr)*64 + (((ks<<2)|lg) ^ rk7)*8]);
#pragma unroll
      for (int i = 0; i < 2; ++i)
#pragma unroll
        for (int j = 0; j < 4; ++j)
          acc[i][j] = mfma16(af[i], bfv[j], acc[i][j]);
    }

    __builtin_amdgcn_sched_barrier(0);
    __builtin_amdgcn_s_barrier();            // all waves done reading cur
    cur ^= 1;
  }

#pragma unroll
  for (int i = 0; i < 2; ++i) {
    const int mBase = m0 + wm + i*16 + 4*lg;
#pragma unroll
    for (int j = 0; j < 4; ++j) {
      const int n = n0 + wn + j*16 + lr;
      float vv[4];
#pragma unroll
      for (int r = 0; r < 4; ++r) {
        const int m = mBase + r;
        float v = acc[i][j][r];
        if (BIAS == 2) v += bias[n];
        if (BIAS == 1) v += bias[m];
        if (EPI == 1 || EPI == 3) v = mask[m] ? v : 0.f;
        if (EPI == 3)  v *= CSC;
        if (EPI == 2)  v = 0.5f * v * (1.f + erff(v * 0.70710678118654752f));
        vv[r] = v;
      }
      if (OUTMODE == 0) {
#pragma unroll
        for (int r = 0; r < 4; ++r)
          ((ushort_t*)Cp)[(size_t)(mBase + r) * N + n] = f2bf(vv[r]);
      } else if (OUTMODE == 1) {
#pragma unroll
        for (int r = 0; r < 4; ++r)
          ((float*)Cp)[(size_t)(mBase + r) * N + n] = vv[r];
      } else if (OUTMODE == 2) {       // Ct[b][n][s], s=m-b*S_ (K/V proj path)
        const int bb = mBase >> 11;
        const int sb = mBase & (S_ - 1);
        ushort_t t4[4] = { f2bf(vv[0]), f2bf(vv[1]), f2bf(vv[2]), f2bf(vv[3]) };
        *reinterpret_cast<short4_t*>(
            (ushort_t*)Cp + ((size_t)bb * D_ + n) * S_ + sb) =
            *reinterpret_cast<short4_t*>(t4);
      } else {                         // Ct[n][m], stride M (linproj V path)
        ushort_t t4[4] = { f2bf(vv[0]), f2bf(vv[1]), f2bf(vv[2]), f2bf(vv[3]) };
        *reinterpret_cast<short4_t*>(
            (ushort_t*)Cp + (size_t)n * M + mBase) =
            *reinterpret_cast<short4_t*>(t4);
      }
    }
  }
}

#define GEMM_SHARED \
  __shared__ __align__(16) ushort_t As[2 * 64 * 64]; \
  __shared__ __align__(16) ushort_t Bs[2 * 128 * 64];

// --------------------------- kernel wrappers -------------------------------
__global__ __launch_bounds__(256) void k_kv(
    const float* __restrict__ bk, const float* __restrict__ bv,
    const int* __restrict__ mask, const ushort_t* __restrict__ ws,
    ushort_t* __restrict__ KbT, ushort_t* __restrict__ VbT)
{
  GEMM_SHARED
  if (blockIdx.z == 0)
    gemmT<2, 1, 2>(As, Bs, ws + XK_OFF, ws + WK_OFF, bk, mask, KbT, B_*S_, D_, D_);
  else
    gemmT<2, 1, 2>(As, Bs, ws + XV_OFF, ws + WV_OFF, bv, mask, VbT, B_*S_, D_, D_);
}

__global__ __launch_bounds__(256) void k_q(
    const float* __restrict__ bq, const int* __restrict__ mask,
    const ushort_t* __restrict__ ws, ushort_t* __restrict__ Qb)
{
  GEMM_SHARED
  gemmT<2, 3, 0>(As, Bs, ws + XQ_OFF, ws + WQ_OFF, bq, mask, Qb, B_*S_, D_, D_);
}

__global__ __launch_bounds__(256) void k_linproj(
    const float* __restrict__ bkP, const float* __restrict__ bvP,
    const ushort_t* __restrict__ ws, const ushort_t* __restrict__ KbT,
    const ushort_t* __restrict__ VbT, ushort_t* __restrict__ Kp,
    ushort_t* __restrict__ VpT)
{
  GEMM_SHARED
  const int z = blockIdx.z, b = z >> 1, isv = z & 1;
  if (isv) {
    gemmT<1, 2, 3>(As, Bs, ws + WVPB_OFF, VbT + (size_t)b * D_ * S_, bvP,
                   nullptr, VpT + (size_t)b * D_ * SP_, SP_, D_, S_);
  } else {
    gemmT<1, 2, 0>(As, Bs, ws + WKPB_OFF, KbT + (size_t)b * D_ * S_, bkP,
                   nullptr, Kp + (size_t)b * SP_ * D_, SP_, D_, S_);
  }
}

__global__ __launch_bounds__(256) void k_outproj(
    const ushort_t* __restrict__ Xo, const ushort_t* __restrict__ Wob,
    const float* __restrict__ bo, float* __restrict__ out)
{
  GEMM_SHARED
  gemmT<2, 0, 1>(As, Bs, Xo, Wob, bo, nullptr, out, B_*S_, D_, D_);
}

// ---------------------------------------------------------------------------
// Fused attention v8 (round-16 structure): 512 thr, QBLK=128, KVBLK=64,
// LDS-staged K/V^T (gload, dbuf, XOR swizzle), counted-vmcnt dual-barrier
// loop (vmcnt(2), no drain), swapped QK^T + cvt_pk P-pack, prescaled-Q exp2,
// per-lane scalar denominator.
// ---------------------------------------------------------------------------
__global__ __launch_bounds__(512) void attn_kernel(
    const ushort_t* __restrict__ Qb, const ushort_t* __restrict__ Kp,
    const ushort_t* __restrict__ VpT, ushort_t* __restrict__ Xo)
{
  __shared__ __align__(16) ushort_t Ks[2][64 * 64];
  __shared__ __align__(16) ushort_t Vs[2][64 * 64];
  __shared__ __align__(16) ushort_t Pl[8][16][72];   // per-wave P [q][p+pad]

  const int b = blockIdx.z, h = blockIdx.y, s0 = blockIdx.x * 128;
  const int tid = threadIdx.x, w = tid >> 6, lane = tid & 63;
  const int lr = lane & 15, lg = lane >> 4;

  const ushort_t* qp = Qb + (size_t)(b * S_ + s0 + w*16 + lr) * D_ + h * 64;
  const bf16x8 aq0 = ld8(qp + 8*lg);        // d = 0..31 slice (pre-scaled)
  const bf16x8 aq1 = ld8(qp + 32 + 8*lg);   // d = 32..63 slice

  const ushort_t* kbase = Kp  + (size_t)b * SP_ * D_ + h * 64;
  const ushort_t* vbase = VpT + (size_t)b * D_ * SP_ + (size_t)(h*64) * SP_;

  const int srow = tid >> 3, sch = tid & 7;
  const int schx = (sch ^ (srow & 7)) << 3;
  const int rk7 = lr & 7;

  f32x4 o[4];
#pragma unroll
  for (int dt = 0; dt < 4; ++dt) o[dt] = f32x4{0.f, 0.f, 0.f, 0.f};
  float lsum4[4] = {0.f, 0.f, 0.f, 0.f};    // per-lane (q=lr) partial denoms

  auto stage = [&](int buf, int p0) {
    gload16(kbase + (size_t)(p0 + srow) * D_ + schx, Ks[buf] + tid*8);
    gload16(vbase + (size_t)srow * SP_ + p0 + schx,  Vs[buf] + tid*8);
  };

  stage(0, 0);
  int cur = 0;
  for (int pt = 0; pt < SP_ / 64; ++pt) {
    if (pt + 1 < SP_ / 64) {
      stage(cur ^ 1, (pt + 1) * 64);
      asm volatile("s_waitcnt vmcnt(2)" ::: "memory");  // cur's 2 loads done
    } else {
      asm volatile("s_waitcnt vmcnt(0)" ::: "memory");
    }
    __builtin_amdgcn_s_barrier();
    __builtin_amdgcn_sched_barrier(0);

    // ---- S^T = K Q^T (swapped); P = exp2(S^T); pack + 1 b64 write/nt ----
#pragma unroll
    for (int nt = 0; nt < 4; ++nt) {
      const ushort_t* krow = Ks[cur] + (nt*16 + lr) * 64;
      f32x4 a = f32x4{0.f, 0.f, 0.f, 0.f};
      a = mfma16(ld8(krow + ((lg       ^ rk7) << 3)), aq0, a);
      a = mfma16(ld8(krow + (((4 + lg) ^ rk7) << 3)), aq1, a);
      const float e0 = __builtin_exp2f(a[0]);
      const float e1 = __builtin_exp2f(a[1]);
      const float e2 = __builtin_exp2f(a[2]);
      const float e3 = __builtin_exp2f(a[3]);
      lsum4[nt] += (e0 + e1) + (e2 + e3);
      unsigned p01, p23;
      asm("v_cvt_pk_bf16_f32 %0, %1, %2" : "=v"(p01) : "v"(e0), "v"(e1));
      asm("v_cvt_pk_bf16_f32 %0, %1, %2" : "=v"(p23) : "v"(e2), "v"(e3));
      uint32x2 pw; pw[0] = p01; pw[1] = p23;
      *reinterpret_cast<uint32x2*>(&Pl[w][lr][nt*16 + 4*lg]) = pw;
    }

    // ---- O += P @ V ----
    const bf16x8 pa0 = ld8(&Pl[w][lr][8*lg]);        // p = 0..31 slice
    const bf16x8 pa1 = ld8(&Pl[w][lr][32 + 8*lg]);   // p = 32..63 slice
#pragma unroll
    for (int dt = 0; dt < 4; ++dt) {
      const ushort_t* vrow = Vs[cur] + (dt*16 + lr) * 64;
      o[dt] = mfma16(pa0, ld8(vrow + ((lg       ^ rk7) << 3)), o[dt]);
      o[dt] = mfma16(pa1, ld8(vrow + (((4 + lg) ^ rk7) << 3)), o[dt]);
    }

    __builtin_amdgcn_sched_barrier(0);
    __builtin_amdgcn_s_barrier();
    cur ^= 1;
  }

  // ---- denominator: reduce 4 lane-groups (same q=lr), then broadcast ----
  float lsum = (lsum4[0] + lsum4[1]) + (lsum4[2] + lsum4[3]);
  lsum += __shfl_xor(lsum, 16, 64);
  lsum += __shfl_xor(lsum, 32, 64);          // every lane: total for q=lr
  float linv[4];
#pragma unroll
  for (int r = 0; r < 4; ++r)
    linv[r] = 1.f / __shfl(lsum, 4*lg + r, 64);   // lane (4lg+r) has q=4lg+r

#pragma unroll
  for (int dt = 0; dt < 4; ++dt)
#pragma unroll
    for (int r = 0; r < 4; ++r) {
      const int srow2 = s0 + w*16 + 4*lg + r;
      Xo[(size_t)(b * S_ + srow2) * D_ + h*64 + dt*16 + lr] =
          f2bf(o[dt][r] * linv[r]);
    }
}

// ------------------------------- launch ------------------------------------
extern "C" void kernel_launch(void* const* d_in, const int* in_sizes, int n_in,
                              void* d_out, int out_size, void* d_ws, size_t ws_size,
                              hipStream_t stream)
{
  const float* q   = (const float*)d_in[0];
  const float* k   = (const float*)d_in[1];
  const float* v   = (const float*)d_in[2];
  const int*   msk = (const int*)d_in[3];
  const float* Wq  = (const float*)d_in[4];
  const float* bq  = (const float*)d_in[5];
  const float* Wk  = (const float*)d_in[6];
  const float* bk  = (const float*)d_in[7];
  const float* Wv  = (const float*)d_in[8];
  const float* bv  = (const float*)d_in[9];
  const float* Wo  = (const float*)d_in[10];
  const float* bo  = (const float*)d_in[11];
  const float* WkP = (const float*)d_in[12];
  const float* bkP = (const float*)d_in[13];
  const float* WvP = (const float*)d_in[14];
  const float* bvP = (const float*)d_in[15];

  ushort_t* ws  = (ushort_t*)d_ws;
  ushort_t* Qb  = ws + QB_OFF;
  ushort_t* Kp  = ws + KP_OFF;
  ushort_t* VpT = ws + VPT_OFF;
  ushort_t* Xo  = ws + XO_OFF;
  ushort_t* KbT = (ushort_t*)d_out;     // d_out as scratch until k_outproj
  ushort_t* VbT = KbT + 4 * M1;

  dim3 blk(256, 1, 1);
  k_convert_a<<<dim3(8192, 1, 1), blk, 0, stream>>>(q, k, v, Wq, Wk, Wv, Wo, ws);
  k_kv     <<<dim3(B_*S_/64, D_/128, 2), blk, 0, stream>>>(bk, bv, msk, ws, KbT, VbT);
  k_q      <<<dim3(B_*S_/64, D_/128, 1), blk, 0, stream>>>(bq, msk, ws, Qb);
  k_convert_b<<<dim3(2048, 1, 1), blk, 0, stream>>>(WkP, WvP, ws);
  k_linproj<<<dim3(SP_/64,  D_/128, 4), blk, 0, stream>>>(bkP, bvP, ws, KbT, VbT, Kp, VpT);
  attn_kernel<<<dim3(S_/128, H_, B_), dim3(512,1,1), 0, stream>>>(Qb, Kp, VpT, Xo);
  k_outproj<<<dim3(B_*S_/64, D_/128, 1), blk, 0, stream>>>(Xo, ws + WO_OFF, bo, (float*)d_out);
}

// Round 18
// 147.876 us; speedup vs baseline: 1.1733x; 1.0446x over previous
//
#include <hip/hip_runtime.h>
#include <hip/hip_bf16.h>

// Linformer MHA, MI355X gfx950. Round 18: consolidation — best-of components.
//   gemmT: round-14/15 single-buffer BK=64 + XOR swizzle + XCD swizzle
//          (24KB LDS -> 6 blocks/CU; T4-dbuf reverted: 48KB -> 3 blocks/CU
//          cost more than the pipeline gained, r17 measured).
//   attn : round-17 counted-vmcnt dual-barrier (38.9 vs 40.2 us, A/B'd).
// Pipeline (stream-ordered aliasing, ws = 32MB exactly):
//   k_convert_a: q,k,v -> Xqb[0:4M) Xkb[4M:8M) Xvb[8M:12M); Wq/Wk/Wv/Wo -> [12M:16M)
//   k_kv   : K/V projections -> KbT/VbT in d_out
//   k_q    : Q projection (masked, pre-scaled by 0.125*log2e) -> Qb @ [4M:8M)
//   k_convert_b: WkP/WvP -> [8M:12M)
//   k_linproj: -> Kp[0:2M) VpT[2M:4M)
//   attn   : -> Xo[8M:12M)
//   k_outproj: -> fp32 d_out

typedef __attribute__((ext_vector_type(4))) float  f32x4;
typedef __attribute__((ext_vector_type(8))) short  short8;
typedef __attribute__((ext_vector_type(4))) short  short4_t;
typedef __attribute__((ext_vector_type(2))) unsigned int uint32x2;
typedef __attribute__((ext_vector_type(8))) __bf16 bf16x8;
typedef unsigned short ushort_t;

#define DEV __device__ __forceinline__

constexpr int B_ = 2, S_ = 2048, D_ = 1024, H_ = 16, SP_ = 1024;
constexpr size_t M1 = 1u << 20;
constexpr size_t XQ_OFF = 0,      XK_OFF = 4*M1,  XV_OFF = 8*M1,
                 WQ_OFF = 12*M1,  WK_OFF = 13*M1, WV_OFF = 14*M1, WO_OFF = 15*M1,
                 QB_OFF = 4*M1,   KP_OFF = 0,     VPT_OFF = 2*M1,
                 WKPB_OFF = 8*M1, WVPB_OFF = 10*M1, XO_OFF = 8*M1;
constexpr float CSC = 0.18033688011112042f;   // 0.125 * log2(e)

DEV ushort_t f2bf(float f) {              // RNE fp32 -> bf16 bits
  unsigned u = __builtin_bit_cast(unsigned, f);
  unsigned r = ((u >> 16) & 1u) + 0x7FFFu;
  return (ushort_t)((u + r) >> 16);
}
DEV bf16x8 ld8(const ushort_t* p) {
  return __builtin_bit_cast(bf16x8, *reinterpret_cast<const short8*>(p));
}
DEV f32x4 mfma16(bf16x8 a, bf16x8 b, f32x4 c) {
  return __builtin_amdgcn_mfma_f32_16x16x32_bf16(a, b, c, 0, 0, 0);
}
DEV void gload16(const ushort_t* g, ushort_t* l) {   // 16B global -> LDS direct
  __builtin_amdgcn_global_load_lds(
      (const __attribute__((address_space(1))) void*)g,
      (__attribute__((address_space(3))) void*)l, 16, 0, 0);
}
DEV void cvt2048(const float* src, ushort_t* dst, int tid) {
  const size_t off = (size_t)tid * 8;
  float4 f0 = *reinterpret_cast<const float4*>(src + off);
  float4 f1 = *reinterpret_cast<const float4*>(src + off + 4);
  ushort_t t[8] = { f2bf(f0.x), f2bf(f0.y), f2bf(f0.z), f2bf(f0.w),
                    f2bf(f1.x), f2bf(f1.y), f2bf(f1.z), f2bf(f1.w) };
  *reinterpret_cast<short8*>(dst + off) = *reinterpret_cast<short8*>(t);
}

// ---------------------------------------------------------------------------
// Conversion A: q,k,v (12M) + Wq,Wk,Wv,Wo (4M) -> bf16. 8192 blocks x 2048 el.
// ---------------------------------------------------------------------------
__global__ __launch_bounds__(256) void k_convert_a(
    const float* __restrict__ q, const float* __restrict__ k,
    const float* __restrict__ v, const float* __restrict__ Wq,
    const float* __restrict__ Wk, const float* __restrict__ Wv,
    const float* __restrict__ Wo, ushort_t* __restrict__ ws)
{
  int blk = blockIdx.x; const float* src; ushort_t* dst;
  if      (blk < 2048) { src = q;  dst = ws + XQ_OFF; }
  else if (blk < 4096) { src = k;  dst = ws + XK_OFF; blk -= 2048; }
  else if (blk < 6144) { src = v;  dst = ws + XV_OFF; blk -= 4096; }
  else if (blk < 6656) { src = Wq; dst = ws + WQ_OFF; blk -= 6144; }
  else if (blk < 7168) { src = Wk; dst = ws + WK_OFF; blk -= 6656; }
  else if (blk < 7680) { src = Wv; dst = ws + WV_OFF; blk -= 7168; }
  else                 { src = Wo; dst = ws + WO_OFF; blk -= 7680; }
  cvt2048(src + (size_t)blk * 2048, dst + (size_t)blk * 2048, threadIdx.x);
}

// Conversion B: WkP, WvP (4M elems) -> bf16. 2048 blocks.
__global__ __launch_bounds__(256) void k_convert_b(
    const float* __restrict__ WkP, const float* __restrict__ WvP,
    ushort_t* __restrict__ ws)
{
  int blk = blockIdx.x; const float* src; ushort_t* dst;
  if (blk < 1024) { src = WkP; dst = ws + WKPB_OFF; }
  else            { src = WvP; dst = ws + WVPB_OFF; blk -= 1024; }
  cvt2048(src + (size_t)blk * 2048, dst + (size_t)blk * 2048, threadIdx.x);
}

// ---------------------------------------------------------------------------
// 64x128xK bf16 MFMA GEMM, 256 thr (4 waves), BK=64, single-buffered LDS
// (24KB), 128B rows XOR-swizzled, global_load_lds both operands, XCD swizzle.
// EPI: 0 none, 1 mask-row, 2 exact-GELU, 3 mask-row + scale-by-CSC.
// OUTMODE: 0 bf16 C[m][n]; 1 fp32 C[m][n]; 2 bf16 Ct[b][n][s]; 3 bf16 Ct[n][m].
// ---------------------------------------------------------------------------
template<int BIAS, int EPI, int OUTMODE>
DEV void gemmT(const ushort_t* Ap, const ushort_t* Bp, const float* bias,
               const int* mask, void* Cp, int M, int N, int K)
{
  __shared__ __align__(16) ushort_t As[64 * 64];    // 8KB
  __shared__ __align__(16) ushort_t Bs[128 * 64];   // 16KB
  const int tid = threadIdx.x;

  const int gx = gridDim.x, gy = gridDim.y, nwg = gx * gy;
  int lin = blockIdx.y * gx + blockIdx.x;
  lin = (lin & 7) * (nwg >> 3) + (lin >> 3);
  const int m0 = (lin / gy) * 64, n0 = (lin % gy) * 128;

  const int w = tid >> 6, lane = tid & 63, lr = lane & 15, lg = lane >> 4;
  const int wm = (w >> 1) * 32, wn = (w & 1) * 64;
  const int rk7 = lr & 7;

  f32x4 acc[2][4];
#pragma unroll
  for (int i = 0; i < 2; ++i)
#pragma unroll
    for (int j = 0; j < 4; ++j) acc[i][j] = f32x4{0.f, 0.f, 0.f, 0.f};

  const int srow = tid >> 3;                          // 0..31
  const int schx = ((tid & 7) ^ (srow & 7)) * 8;      // pre-swizzled col off
  const ushort_t* Ag = Ap + (size_t)(m0 + srow) * K + schx;
  const ushort_t* Bg = Bp + (size_t)(n0 + srow) * K + schx;

  for (int k0 = 0; k0 < K; k0 += 64) {
    gload16(Ag + k0,                 As + tid*8);
    gload16(Ag + (size_t)32*K + k0,  As + 2048 + tid*8);
    gload16(Bg + k0,                 Bs + tid*8);
    gload16(Bg + (size_t)32*K + k0,  Bs + 2048 + tid*8);
    gload16(Bg + (size_t)64*K + k0,  Bs + 4096 + tid*8);
    gload16(Bg + (size_t)96*K + k0,  Bs + 6144 + tid*8);
    __syncthreads();

#pragma unroll
    for (int ks = 0; ks < 2; ++ks) {
      bf16x8 af[2], bfv[4];
#pragma unroll
      for (int i = 0; i < 2; ++i)
        af[i]  = ld8(&As[(wm + i*16 + lr)*64 + (((ks<<2)|lg) ^ rk7)*8]);
#pragma unroll
      for (int j = 0; j < 4; ++j)
        bfv[j] = ld8(&Bs[(wn + j*16 + lr)*64 + (((ks<<2)|lg) ^ rk7)*8]);
#pragma unroll
      for (int i = 0; i < 2; ++i)
#pragma unroll
        for (int j = 0; j < 4; ++j)
          acc[i][j] = mfma16(af[i], bfv[j], acc[i][j]);
    }
    __syncthreads();
  }

#pragma unroll
  for (int i = 0; i < 2; ++i) {
    const int mBase = m0 + wm + i*16 + 4*lg;
#pragma unroll
    for (int j = 0; j < 4; ++j) {
      const int n = n0 + wn + j*16 + lr;
      float vv[4];
#pragma unroll
      for (int r = 0; r < 4; ++r) {
        const int m = mBase + r;
        float v = acc[i][j][r];
        if (BIAS == 2) v += bias[n];
        if (BIAS == 1) v += bias[m];
        if (EPI == 1 || EPI == 3) v = mask[m] ? v : 0.f;
        if (EPI == 3)  v *= CSC;
        if (EPI == 2)  v = 0.5f * v * (1.f + erff(v * 0.70710678118654752f));
        vv[r] = v;
      }
      if (OUTMODE == 0) {
#pragma unroll
        for (int r = 0; r < 4; ++r)
          ((ushort_t*)Cp)[(size_t)(mBase + r) * N + n] = f2bf(vv[r]);
      } else if (OUTMODE == 1) {
#pragma unroll
        for (int r = 0; r < 4; ++r)
          ((float*)Cp)[(size_t)(mBase + r) * N + n] = vv[r];
      } else if (OUTMODE == 2) {       // Ct[b][n][s], s=m-b*S_ (K/V proj path)
        const int bb = mBase >> 11;
        const int sb = mBase & (S_ - 1);
        ushort_t t4[4] = { f2bf(vv[0]), f2bf(vv[1]), f2bf(vv[2]), f2bf(vv[3]) };
        *reinterpret_cast<short4_t*>(
            (ushort_t*)Cp + ((size_t)bb * D_ + n) * S_ + sb) =
            *reinterpret_cast<short4_t*>(t4);
      } else {                         // Ct[n][m], stride M (linproj V path)
        ushort_t t4[4] = { f2bf(vv[0]), f2bf(vv[1]), f2bf(vv[2]), f2bf(vv[3]) };
        *reinterpret_cast<short4_t*>(
            (ushort_t*)Cp + (size_t)n * M + mBase) =
            *reinterpret_cast<short4_t*>(t4);
      }
    }
  }
}

// --------------------------- kernel wrappers -------------------------------
__global__ __launch_bounds__(256) void k_kv(
    const float* __restrict__ bk, const float* __restrict__ bv,
    const int* __restrict__ mask, const ushort_t* __restrict__ ws,
    ushort_t* __restrict__ KbT, ushort_t* __restrict__ VbT)
{
  if (blockIdx.z == 0)
    gemmT<2, 1, 2>(ws + XK_OFF, ws + WK_OFF, bk, mask, KbT, B_*S_, D_, D_);
  else
    gemmT<2, 1, 2>(ws + XV_OFF, ws + WV_OFF, bv, mask, VbT, B_*S_, D_, D_);
}

__global__ __launch_bounds__(256) void k_q(
    const float* __restrict__ bq, const int* __restrict__ mask,
    const ushort_t* __restrict__ ws, ushort_t* __restrict__ Qb)
{
  gemmT<2, 3, 0>(ws + XQ_OFF, ws + WQ_OFF, bq, mask, Qb, B_*S_, D_, D_);
}

__global__ __launch_bounds__(256) void k_linproj(
    const float* __restrict__ bkP, const float* __restrict__ bvP,
    const ushort_t* __restrict__ ws, const ushort_t* __restrict__ KbT,
    const ushort_t* __restrict__ VbT, ushort_t* __restrict__ Kp,
    ushort_t* __restrict__ VpT)
{
  const int z = blockIdx.z, b = z >> 1, isv = z & 1;
  if (isv) {
    gemmT<1, 2, 3>(ws + WVPB_OFF, VbT + (size_t)b * D_ * S_, bvP,
                   nullptr, VpT + (size_t)b * D_ * SP_, SP_, D_, S_);
  } else {
    gemmT<1, 2, 0>(ws + WKPB_OFF, KbT + (size_t)b * D_ * S_, bkP,
                   nullptr, Kp + (size_t)b * SP_ * D_, SP_, D_, S_);
  }
}

__global__ __launch_bounds__(256) void k_outproj(
    const ushort_t* __restrict__ Xo, const ushort_t* __restrict__ Wob,
    const float* __restrict__ bo, float* __restrict__ out)
{
  gemmT<2, 0, 1>(Xo, Wob, bo, nullptr, out, B_*S_, D_, D_);
}

// ---------------------------------------------------------------------------
// Fused attention (round-17 structure, best): 512 thr, QBLK=128, KVBLK=64,
// LDS-staged K/V^T (gload, dbuf, XOR swizzle), counted-vmcnt dual-barrier
// loop (vmcnt(2), no drain), swapped QK^T + cvt_pk P-pack, prescaled-Q exp2,
// per-lane scalar denominator.
// ---------------------------------------------------------------------------
__global__ __launch_bounds__(512) void attn_kernel(
    const ushort_t* __restrict__ Qb, const ushort_t* __restrict__ Kp,
    const ushort_t* __restrict__ VpT, ushort_t* __restrict__ Xo)
{
  __shared__ __align__(16) ushort_t Ks[2][64 * 64];
  __shared__ __align__(16) ushort_t Vs[2][64 * 64];
  __shared__ __align__(16) ushort_t Pl[8][16][72];   // per-wave P [q][p+pad]

  const int b = blockIdx.z, h = blockIdx.y, s0 = blockIdx.x * 128;
  const int tid = threadIdx.x, w = tid >> 6, lane = tid & 63;
  const int lr = lane & 15, lg = lane >> 4;

  const ushort_t* qp = Qb + (size_t)(b * S_ + s0 + w*16 + lr) * D_ + h * 64;
  const bf16x8 aq0 = ld8(qp + 8*lg);        // d = 0..31 slice (pre-scaled)
  const bf16x8 aq1 = ld8(qp + 32 + 8*lg);   // d = 32..63 slice

  const ushort_t* kbase = Kp  + (size_t)b * SP_ * D_ + h * 64;
  const ushort_t* vbase = VpT + (size_t)b * D_ * SP_ + (size_t)(h*64) * SP_;

  const int srow = tid >> 3, sch = tid & 7;
  const int schx = (sch ^ (srow & 7)) << 3;
  const int rk7 = lr & 7;

  f32x4 o[4];
#pragma unroll
  for (int dt = 0; dt < 4; ++dt) o[dt] = f32x4{0.f, 0.f, 0.f, 0.f};
  float lsum4[4] = {0.f, 0.f, 0.f, 0.f};    // per-lane (q=lr) partial denoms

  auto stage = [&](int buf, int p0) {
    gload16(kbase + (size_t)(p0 + srow) * D_ + schx, Ks[buf] + tid*8);
    gload16(vbase + (size_t)srow * SP_ + p0 + schx,  Vs[buf] + tid*8);
  };

  stage(0, 0);
  int cur = 0;
  for (int pt = 0; pt < SP_ / 64; ++pt) {
    if (pt + 1 < SP_ / 64) {
      stage(cur ^ 1, (pt + 1) * 64);
      asm volatile("s_waitcnt vmcnt(2)" ::: "memory");  // cur's 2 loads done
    } else {
      asm volatile("s_waitcnt vmcnt(0)" ::: "memory");
    }
    __builtin_amdgcn_s_barrier();
    __builtin_amdgcn_sched_barrier(0);

    // ---- S^T = K Q^T (swapped); P = exp2(S^T); pack + 1 b64 write/nt ----
#pragma unroll
    for (int nt = 0; nt < 4; ++nt) {
      const ushort_t* krow = Ks[cur] + (nt*16 + lr) * 64;
      f32x4 a = f32x4{0.f, 0.f, 0.f, 0.f};
      a = mfma16(ld8(krow + ((lg       ^ rk7) << 3)), aq0, a);
      a = mfma16(ld8(krow + (((4 + lg) ^ rk7) << 3)), aq1, a);
      const float e0 = __builtin_exp2f(a[0]);
      const float e1 = __builtin_exp2f(a[1]);
      const float e2 = __builtin_exp2f(a[2]);
      const float e3 = __builtin_exp2f(a[3]);
      lsum4[nt] += (e0 + e1) + (e2 + e3);
      unsigned p01, p23;
      asm("v_cvt_pk_bf16_f32 %0, %1, %2" : "=v"(p01) : "v"(e0), "v"(e1));
      asm("v_cvt_pk_bf16_f32 %0, %1, %2" : "=v"(p23) : "v"(e2), "v"(e3));
      uint32x2 pw; pw[0] = p01; pw[1] = p23;
      *reinterpret_cast<uint32x2*>(&Pl[w][lr][nt*16 + 4*lg]) = pw;
    }

    // ---- O += P @ V ----
    const bf16x8 pa0 = ld8(&Pl[w][lr][8*lg]);        // p = 0..31 slice
    const bf16x8 pa1 = ld8(&Pl[w][lr][32 + 8*lg]);   // p = 32..63 slice
#pragma unroll
    for (int dt = 0; dt < 4; ++dt) {
      const ushort_t* vrow = Vs[cur] + (dt*16 + lr) * 64;
      o[dt] = mfma16(pa0, ld8(vrow + ((lg       ^ rk7) << 3)), o[dt]);
      o[dt] = mfma16(pa1, ld8(vrow + (((4 + lg) ^ rk7) << 3)), o[dt]);
    }

    __builtin_amdgcn_sched_barrier(0);
    __builtin_amdgcn_s_barrier();
    cur ^= 1;
  }

  // ---- denominator: reduce 4 lane-groups (same q=lr), then broadcast ----
  float lsum = (lsum4[0] + lsum4[1]) + (lsum4[2] + lsum4[3]);
  lsum += __shfl_xor(lsum, 16, 64);
  lsum += __shfl_xor(lsum, 32, 64);          // every lane: total for q=lr
  float linv[4];
#pragma unroll
  for (int r = 0; r < 4; ++r)
    linv[r] = 1.f / __shfl(lsum, 4*lg + r, 64);   // lane (4lg+r) has q=4lg+r

#pragma unroll
  for (int dt = 0; dt < 4; ++dt)
#pragma unroll
    for (int r = 0; r < 4; ++r) {
      const int srow2 = s0 + w*16 + 4*lg + r;
      Xo[(size_t)(b * S_ + srow2) * D_ + h*64 + dt*16 + lr] =
          f2bf(o[dt][r] * linv[r]);
    }
}

// ------------------------------- launch ------------------------------------
extern "C" void kernel_launch(void* const* d_in, const int* in_sizes, int n_in,
                              void* d_out, int out_size, void* d_ws, size_t ws_size,
                              hipStream_t stream)
{
  const float* q   = (const float*)d_in[0];
  const float* k   = (const float*)d_in[1];
  const float* v   = (const float*)d_in[2];
  const int*   msk = (const int*)d_in[3];
  const float* Wq  = (const float*)d_in[4];
  const float* bq  = (const float*)d_in[5];
  const float* Wk  = (const float*)d_in[6];
  const float* bk  = (const float*)d_in[7];
  const float* Wv  = (const float*)d_in[8];
  const float* bv  = (const float*)d_in[9];
  const float* Wo  = (const float*)d_in[10];
  const float* bo  = (const float*)d_in[11];
  const float* WkP = (const float*)d_in[12];
  const float* bkP = (const float*)d_in[13];
  const float* WvP = (const float*)d_in[14];
  const float* bvP = (const float*)d_in[15];

  ushort_t* ws  = (ushort_t*)d_ws;
  ushort_t* Qb  = ws + QB_OFF;
  ushort_t* Kp  = ws + KP_OFF;
  ushort_t* VpT = ws + VPT_OFF;
  ushort_t* Xo  = ws + XO_OFF;
  ushort_t* KbT = (ushort_t*)d_out;     // d_out as scratch until k_outproj
  ushort_t* VbT = KbT + 4 * M1;

  dim3 blk(256, 1, 1);
  k_convert_a<<<dim3(8192, 1, 1), blk, 0, stream>>>(q, k, v, Wq, Wk, Wv, Wo, ws);
  k_kv     <<<dim3(B_*S_/64, D_/128, 2), blk, 0, stream>>>(bk, bv, msk, ws, KbT, VbT);
  k_q      <<<dim3(B_*S_/64, D_/128, 1), blk, 0, stream>>>(bq, msk, ws, Qb);
  k_convert_b<<<dim3(2048, 1, 1), blk, 0, stream>>>(WkP, WvP, ws);
  k_linproj<<<dim3(SP_/64,  D_/128, 4), blk, 0, stream>>>(bkP, bvP, ws, KbT, VbT, Kp, VpT);
  attn_kernel<<<dim3(S_/128, H_, B_), dim3(512,1,1), 0, stream>>>(Qb, Kp, VpT, Xo);
  k_outproj<<<dim3(B_*S_/64, D_/128, 1), blk, 0, stream>>>(Xo, ws + WO_OFF, bo, (float*)d_out);
}

// Round 19
// 146.517 us; speedup vs baseline: 1.1842x; 1.0093x over previous
//
#include <hip/hip_runtime.h>
#include <hip/hip_bf16.h>

// Linformer MHA, MI355X gfx950. Round 19: r18 + attn-only T5 setprio (phase-
// split schedule -> scheduler can favor MFMA waves) + bijective XCD tile
// remap for attn (each XCD owns 4 complete (b,h) groups -> K/V L2-resident,
// 2MB/XCD). GEMMs unchanged (T5 measured null on lockstep GEMM schedules).
// Pipeline (stream-ordered aliasing, ws = 32MB exactly):
//   k_convert_a: q,k,v -> Xqb[0:4M) Xkb[4M:8M) Xvb[8M:12M); Wq/Wk/Wv/Wo -> [12M:16M)
//   k_kv   : K/V projections -> KbT/VbT in d_out
//   k_q    : Q projection (masked, pre-scaled by 0.125*log2e) -> Qb @ [4M:8M)
//   k_convert_b: WkP/WvP -> [8M:12M)
//   k_linproj: -> Kp[0:2M) VpT[2M:4M)
//   attn   : -> Xo[8M:12M)
//   k_outproj: -> fp32 d_out

typedef __attribute__((ext_vector_type(4))) float  f32x4;
typedef __attribute__((ext_vector_type(8))) short  short8;
typedef __attribute__((ext_vector_type(4))) short  short4_t;
typedef __attribute__((ext_vector_type(2))) unsigned int uint32x2;
typedef __attribute__((ext_vector_type(8))) __bf16 bf16x8;
typedef unsigned short ushort_t;

#define DEV __device__ __forceinline__

constexpr int B_ = 2, S_ = 2048, D_ = 1024, H_ = 16, SP_ = 1024;
constexpr size_t M1 = 1u << 20;
constexpr size_t XQ_OFF = 0,      XK_OFF = 4*M1,  XV_OFF = 8*M1,
                 WQ_OFF = 12*M1,  WK_OFF = 13*M1, WV_OFF = 14*M1, WO_OFF = 15*M1,
                 QB_OFF = 4*M1,   KP_OFF = 0,     VPT_OFF = 2*M1,
                 WKPB_OFF = 8*M1, WVPB_OFF = 10*M1, XO_OFF = 8*M1;
constexpr float CSC = 0.18033688011112042f;   // 0.125 * log2(e)

DEV ushort_t f2bf(float f) {              // RNE fp32 -> bf16 bits
  unsigned u = __builtin_bit_cast(unsigned, f);
  unsigned r = ((u >> 16) & 1u) + 0x7FFFu;
  return (ushort_t)((u + r) >> 16);
}
DEV bf16x8 ld8(const ushort_t* p) {
  return __builtin_bit_cast(bf16x8, *reinterpret_cast<const short8*>(p));
}
DEV f32x4 mfma16(bf16x8 a, bf16x8 b, f32x4 c) {
  return __builtin_amdgcn_mfma_f32_16x16x32_bf16(a, b, c, 0, 0, 0);
}
DEV void gload16(const ushort_t* g, ushort_t* l) {   // 16B global -> LDS direct
  __builtin_amdgcn_global_load_lds(
      (const __attribute__((address_space(1))) void*)g,
      (__attribute__((address_space(3))) void*)l, 16, 0, 0);
}
DEV void cvt2048(const float* src, ushort_t* dst, int tid) {
  const size_t off = (size_t)tid * 8;
  float4 f0 = *reinterpret_cast<const float4*>(src + off);
  float4 f1 = *reinterpret_cast<const float4*>(src + off + 4);
  ushort_t t[8] = { f2bf(f0.x), f2bf(f0.y), f2bf(f0.z), f2bf(f0.w),
                    f2bf(f1.x), f2bf(f1.y), f2bf(f1.z), f2bf(f1.w) };
  *reinterpret_cast<short8*>(dst + off) = *reinterpret_cast<short8*>(t);
}

// ---------------------------------------------------------------------------
// Conversion A: q,k,v (12M) + Wq,Wk,Wv,Wo (4M) -> bf16. 8192 blocks x 2048 el.
// ---------------------------------------------------------------------------
__global__ __launch_bounds__(256) void k_convert_a(
    const float* __restrict__ q, const float* __restrict__ k,
    const float* __restrict__ v, const float* __restrict__ Wq,
    const float* __restrict__ Wk, const float* __restrict__ Wv,
    const float* __restrict__ Wo, ushort_t* __restrict__ ws)
{
  int blk = blockIdx.x; const float* src; ushort_t* dst;
  if      (blk < 2048) { src = q;  dst = ws + XQ_OFF; }
  else if (blk < 4096) { src = k;  dst = ws + XK_OFF; blk -= 2048; }
  else if (blk < 6144) { src = v;  dst = ws + XV_OFF; blk -= 4096; }
  else if (blk < 6656) { src = Wq; dst = ws + WQ_OFF; blk -= 6144; }
  else if (blk < 7168) { src = Wk; dst = ws + WK_OFF; blk -= 6656; }
  else if (blk < 7680) { src = Wv; dst = ws + WV_OFF; blk -= 7168; }
  else                 { src = Wo; dst = ws + WO_OFF; blk -= 7680; }
  cvt2048(src + (size_t)blk * 2048, dst + (size_t)blk * 2048, threadIdx.x);
}

// Conversion B: WkP, WvP (4M elems) -> bf16. 2048 blocks.
__global__ __launch_bounds__(256) void k_convert_b(
    const float* __restrict__ WkP, const float* __restrict__ WvP,
    ushort_t* __restrict__ ws)
{
  int blk = blockIdx.x; const float* src; ushort_t* dst;
  if (blk < 1024) { src = WkP; dst = ws + WKPB_OFF; }
  else            { src = WvP; dst = ws + WVPB_OFF; blk -= 1024; }
  cvt2048(src + (size_t)blk * 2048, dst + (size_t)blk * 2048, threadIdx.x);
}

// ---------------------------------------------------------------------------
// 64x128xK bf16 MFMA GEMM, 256 thr (4 waves), BK=64, single-buffered LDS
// (24KB), 128B rows XOR-swizzled, global_load_lds both operands, XCD swizzle.
// EPI: 0 none, 1 mask-row, 2 exact-GELU, 3 mask-row + scale-by-CSC.
// OUTMODE: 0 bf16 C[m][n]; 1 fp32 C[m][n]; 2 bf16 Ct[b][n][s]; 3 bf16 Ct[n][m].
// ---------------------------------------------------------------------------
template<int BIAS, int EPI, int OUTMODE>
DEV void gemmT(const ushort_t* Ap, const ushort_t* Bp, const float* bias,
               const int* mask, void* Cp, int M, int N, int K)
{
  __shared__ __align__(16) ushort_t As[64 * 64];    // 8KB
  __shared__ __align__(16) ushort_t Bs[128 * 64];   // 16KB
  const int tid = threadIdx.x;

  const int gx = gridDim.x, gy = gridDim.y, nwg = gx * gy;
  int lin = blockIdx.y * gx + blockIdx.x;
  lin = (lin & 7) * (nwg >> 3) + (lin >> 3);
  const int m0 = (lin / gy) * 64, n0 = (lin % gy) * 128;

  const int w = tid >> 6, lane = tid & 63, lr = lane & 15, lg = lane >> 4;
  const int wm = (w >> 1) * 32, wn = (w & 1) * 64;
  const int rk7 = lr & 7;

  f32x4 acc[2][4];
#pragma unroll
  for (int i = 0; i < 2; ++i)
#pragma unroll
    for (int j = 0; j < 4; ++j) acc[i][j] = f32x4{0.f, 0.f, 0.f, 0.f};

  const int srow = tid >> 3;                          // 0..31
  const int schx = ((tid & 7) ^ (srow & 7)) * 8;      // pre-swizzled col off
  const ushort_t* Ag = Ap + (size_t)(m0 + srow) * K + schx;
  const ushort_t* Bg = Bp + (size_t)(n0 + srow) * K + schx;

  for (int k0 = 0; k0 < K; k0 += 64) {
    gload16(Ag + k0,                 As + tid*8);
    gload16(Ag + (size_t)32*K + k0,  As + 2048 + tid*8);
    gload16(Bg + k0,                 Bs + tid*8);
    gload16(Bg + (size_t)32*K + k0,  Bs + 2048 + tid*8);
    gload16(Bg + (size_t)64*K + k0,  Bs + 4096 + tid*8);
    gload16(Bg + (size_t)96*K + k0,  Bs + 6144 + tid*8);
    __syncthreads();

#pragma unroll
    for (int ks = 0; ks < 2; ++ks) {
      bf16x8 af[2], bfv[4];
#pragma unroll
      for (int i = 0; i < 2; ++i)
        af[i]  = ld8(&As[(wm + i*16 + lr)*64 + (((ks<<2)|lg) ^ rk7)*8]);
#pragma unroll
      for (int j = 0; j < 4; ++j)
        bfv[j] = ld8(&Bs[(wn + j*16 + lr)*64 + (((ks<<2)|lg) ^ rk7)*8]);
#pragma unroll
      for (int i = 0; i < 2; ++i)
#pragma unroll
        for (int j = 0; j < 4; ++j)
          acc[i][j] = mfma16(af[i], bfv[j], acc[i][j]);
    }
    __syncthreads();
  }

#pragma unroll
  for (int i = 0; i < 2; ++i) {
    const int mBase = m0 + wm + i*16 + 4*lg;
#pragma unroll
    for (int j = 0; j < 4; ++j) {
      const int n = n0 + wn + j*16 + lr;
      float vv[4];
#pragma unroll
      for (int r = 0; r < 4; ++r) {
        const int m = mBase + r;
        float v = acc[i][j][r];
        if (BIAS == 2) v += bias[n];
        if (BIAS == 1) v += bias[m];
        if (EPI == 1 || EPI == 3) v = mask[m] ? v : 0.f;
        if (EPI == 3)  v *= CSC;
        if (EPI == 2)  v = 0.5f * v * (1.f + erff(v * 0.70710678118654752f));
        vv[r] = v;
      }
      if (OUTMODE == 0) {
#pragma unroll
        for (int r = 0; r < 4; ++r)
          ((ushort_t*)Cp)[(size_t)(mBase + r) * N + n] = f2bf(vv[r]);
      } else if (OUTMODE == 1) {
#pragma unroll
        for (int r = 0; r < 4; ++r)
          ((float*)Cp)[(size_t)(mBase + r) * N + n] = vv[r];
      } else if (OUTMODE == 2) {       // Ct[b][n][s], s=m-b*S_ (K/V proj path)
        const int bb = mBase >> 11;
        const int sb = mBase & (S_ - 1);
        ushort_t t4[4] = { f2bf(vv[0]), f2bf(vv[1]), f2bf(vv[2]), f2bf(vv[3]) };
        *reinterpret_cast<short4_t*>(
            (ushort_t*)Cp + ((size_t)bb * D_ + n) * S_ + sb) =
            *reinterpret_cast<short4_t*>(t4);
      } else {                         // Ct[n][m], stride M (linproj V path)
        ushort_t t4[4] = { f2bf(vv[0]), f2bf(vv[1]), f2bf(vv[2]), f2bf(vv[3]) };
        *reinterpret_cast<short4_t*>(
            (ushort_t*)Cp + (size_t)n * M + mBase) =
            *reinterpret_cast<short4_t*>(t4);
      }
    }
  }
}

// --------------------------- kernel wrappers -------------------------------
__global__ __launch_bounds__(256) void k_kv(
    const float* __restrict__ bk, const float* __restrict__ bv,
    const int* __restrict__ mask, const ushort_t* __restrict__ ws,
    ushort_t* __restrict__ KbT, ushort_t* __restrict__ VbT)
{
  if (blockIdx.z == 0)
    gemmT<2, 1, 2>(ws + XK_OFF, ws + WK_OFF, bk, mask, KbT, B_*S_, D_, D_);
  else
    gemmT<2, 1, 2>(ws + XV_OFF, ws + WV_OFF, bv, mask, VbT, B_*S_, D_, D_);
}

__global__ __launch_bounds__(256) void k_q(
    const float* __restrict__ bq, const int* __restrict__ mask,
    const ushort_t* __restrict__ ws, ushort_t* __restrict__ Qb)
{
  gemmT<2, 3, 0>(ws + XQ_OFF, ws + WQ_OFF, bq, mask, Qb, B_*S_, D_, D_);
}

__global__ __launch_bounds__(256) void k_linproj(
    const float* __restrict__ bkP, const float* __restrict__ bvP,
    const ushort_t* __restrict__ ws, const ushort_t* __restrict__ KbT,
    const ushort_t* __restrict__ VbT, ushort_t* __restrict__ Kp,
    ushort_t* __restrict__ VpT)
{
  const int z = blockIdx.z, b = z >> 1, isv = z & 1;
  if (isv) {
    gemmT<1, 2, 3>(ws + WVPB_OFF, VbT + (size_t)b * D_ * S_, bvP,
                   nullptr, VpT + (size_t)b * D_ * SP_, SP_, D_, S_);
  } else {
    gemmT<1, 2, 0>(ws + WKPB_OFF, KbT + (size_t)b * D_ * S_, bkP,
                   nullptr, Kp + (size_t)b * SP_ * D_, SP_, D_, S_);
  }
}

__global__ __launch_bounds__(256) void k_outproj(
    const ushort_t* __restrict__ Xo, const ushort_t* __restrict__ Wob,
    const float* __restrict__ bo, float* __restrict__ out)
{
  gemmT<2, 0, 1>(Xo, Wob, bo, nullptr, out, B_*S_, D_, D_);
}

// ---------------------------------------------------------------------------
// Fused attention (r17 structure + T5 setprio + XCD tile remap): 512 thr,
// QBLK=128, KVBLK=64, LDS-staged K/V^T (gload, dbuf, XOR swizzle),
// counted-vmcnt dual-barrier loop, swapped QK^T + cvt_pk P-pack,
// prescaled-Q exp2, per-lane scalar denominator.
// 1D grid of 512; tile remap (lin&7)*64 + (lin>>3): each XCD owns 64
// consecutive tiles = 4 complete (b,h) groups -> K/V stays in its L2 (2MB).
// ---------------------------------------------------------------------------
__global__ __launch_bounds__(512) void attn_kernel(
    const ushort_t* __restrict__ Qb, const ushort_t* __restrict__ Kp,
    const ushort_t* __restrict__ VpT, ushort_t* __restrict__ Xo)
{
  __shared__ __align__(16) ushort_t Ks[2][64 * 64];
  __shared__ __align__(16) ushort_t Vs[2][64 * 64];
  __shared__ __align__(16) ushort_t Pl[8][16][72];   // per-wave P [q][p+pad]

  // XCD tile remap: 512 tiles = 8 XCDs x 64; tile id = (lin&7)*64 + lin>>3.
  const int lin = blockIdx.x;
  const int tile = (lin & 7) * 64 + (lin >> 3);
  const int s0 = (tile & 15) * 128;          // s-fastest within (b,h)
  const int h  = (tile >> 4) & 15;
  const int b  = tile >> 8;

  const int tid = threadIdx.x, w = tid >> 6, lane = tid & 63;
  const int lr = lane & 15, lg = lane >> 4;

  const ushort_t* qp = Qb + (size_t)(b * S_ + s0 + w*16 + lr) * D_ + h * 64;
  const bf16x8 aq0 = ld8(qp + 8*lg);        // d = 0..31 slice (pre-scaled)
  const bf16x8 aq1 = ld8(qp + 32 + 8*lg);   // d = 32..63 slice

  const ushort_t* kbase = Kp  + (size_t)b * SP_ * D_ + h * 64;
  const ushort_t* vbase = VpT + (size_t)b * D_ * SP_ + (size_t)(h*64) * SP_;

  const int srow = tid >> 3, sch = tid & 7;
  const int schx = (sch ^ (srow & 7)) << 3;
  const int rk7 = lr & 7;

  f32x4 o[4];
#pragma unroll
  for (int dt = 0; dt < 4; ++dt) o[dt] = f32x4{0.f, 0.f, 0.f, 0.f};
  float lsum4[4] = {0.f, 0.f, 0.f, 0.f};    // per-lane (q=lr) partial denoms

  auto stage = [&](int buf, int p0) {
    gload16(kbase + (size_t)(p0 + srow) * D_ + schx, Ks[buf] + tid*8);
    gload16(vbase + (size_t)srow * SP_ + p0 + schx,  Vs[buf] + tid*8);
  };

  stage(0, 0);
  int cur = 0;
  for (int pt = 0; pt < SP_ / 64; ++pt) {
    if (pt + 1 < SP_ / 64) {
      stage(cur ^ 1, (pt + 1) * 64);
      asm volatile("s_waitcnt vmcnt(2)" ::: "memory");  // cur's 2 loads done
    } else {
      asm volatile("s_waitcnt vmcnt(0)" ::: "memory");
    }
    __builtin_amdgcn_s_barrier();
    __builtin_amdgcn_sched_barrier(0);
    __builtin_amdgcn_s_setprio(1);

    // ---- S^T = K Q^T (swapped); P = exp2(S^T); pack + 1 b64 write/nt ----
#pragma unroll
    for (int nt = 0; nt < 4; ++nt) {
      const ushort_t* krow = Ks[cur] + (nt*16 + lr) * 64;
      f32x4 a = f32x4{0.f, 0.f, 0.f, 0.f};
      a = mfma16(ld8(krow + ((lg       ^ rk7) << 3)), aq0, a);
      a = mfma16(ld8(krow + (((4 + lg) ^ rk7) << 3)), aq1, a);
      const float e0 = __builtin_exp2f(a[0]);
      const float e1 = __builtin_exp2f(a[1]);
      const float e2 = __builtin_exp2f(a[2]);
      const float e3 = __builtin_exp2f(a[3]);
      lsum4[nt] += (e0 + e1) + (e2 + e3);
      unsigned p01, p23;
      asm("v_cvt_pk_bf16_f32 %0, %1, %2" : "=v"(p01) : "v"(e0), "v"(e1));
      asm("v_cvt_pk_bf16_f32 %0, %1, %2" : "=v"(p23) : "v"(e2), "v"(e3));
      uint32x2 pw; pw[0] = p01; pw[1] = p23;
      *reinterpret_cast<uint32x2*>(&Pl[w][lr][nt*16 + 4*lg]) = pw;
    }

    // ---- O += P @ V ----
    const bf16x8 pa0 = ld8(&Pl[w][lr][8*lg]);        // p = 0..31 slice
    const bf16x8 pa1 = ld8(&Pl[w][lr][32 + 8*lg]);   // p = 32..63 slice
#pragma unroll
    for (int dt = 0; dt < 4; ++dt) {
      const ushort_t* vrow = Vs[cur] + (dt*16 + lr) * 64;
      o[dt] = mfma16(pa0, ld8(vrow + ((lg       ^ rk7) << 3)), o[dt]);
      o[dt] = mfma16(pa1, ld8(vrow + (((4 + lg) ^ rk7) << 3)), o[dt]);
    }

    __builtin_amdgcn_s_setprio(0);
    __builtin_amdgcn_sched_barrier(0);
    __builtin_amdgcn_s_barrier();
    cur ^= 1;
  }

  // ---- denominator: reduce 4 lane-groups (same q=lr), then broadcast ----
  float lsum = (lsum4[0] + lsum4[1]) + (lsum4[2] + lsum4[3]);
  lsum += __shfl_xor(lsum, 16, 64);
  lsum += __shfl_xor(lsum, 32, 64);          // every lane: total for q=lr
  float linv[4];
#pragma unroll
  for (int r = 0; r < 4; ++r)
    linv[r] = 1.f / __shfl(lsum, 4*lg + r, 64);   // lane (4lg+r) has q=4lg+r

#pragma unroll
  for (int dt = 0; dt < 4; ++dt)
#pragma unroll
    for (int r = 0; r < 4; ++r) {
      const int srow2 = s0 + w*16 + 4*lg + r;
      Xo[(size_t)(b * S_ + srow2) * D_ + h*64 + dt*16 + lr] =
          f2bf(o[dt][r] * linv[r]);
    }
}

// ------------------------------- launch ------------------------------------
extern "C" void kernel_launch(void* const* d_in, const int* in_sizes, int n_in,
                              void* d_out, int out_size, void* d_ws, size_t ws_size,
                              hipStream_t stream)
{
  const float* q   = (const float*)d_in[0];
  const float* k   = (const float*)d_in[1];
  const float* v   = (const float*)d_in[2];
  const int*   msk = (const int*)d_in[3];
  const float* Wq  = (const float*)d_in[4];
  const float* bq  = (const float*)d_in[5];
  const float* Wk  = (const float*)d_in[6];
  const float* bk  = (const float*)d_in[7];
  const float* Wv  = (const float*)d_in[8];
  const float* bv  = (const float*)d_in[9];
  const float* Wo  = (const float*)d_in[10];
  const float* bo  = (const float*)d_in[11];
  const float* WkP = (const float*)d_in[12];
  const float* bkP = (const float*)d_in[13];
  const float* WvP = (const float*)d_in[14];
  const float* bvP = (const float*)d_in[15];

  ushort_t* ws  = (ushort_t*)d_ws;
  ushort_t* Qb  = ws + QB_OFF;
  ushort_t* Kp  = ws + KP_OFF;
  ushort_t* VpT = ws + VPT_OFF;
  ushort_t* Xo  = ws + XO_OFF;
  ushort_t* KbT = (ushort_t*)d_out;     // d_out as scratch until k_outproj
  ushort_t* VbT = KbT + 4 * M1;

  dim3 blk(256, 1, 1);
  k_convert_a<<<dim3(8192, 1, 1), blk, 0, stream>>>(q, k, v, Wq, Wk, Wv, Wo, ws);
  k_kv     <<<dim3(B_*S_/64, D_/128, 2), blk, 0, stream>>>(bk, bv, msk, ws, KbT, VbT);
  k_q      <<<dim3(B_*S_/64, D_/128, 1), blk, 0, stream>>>(bq, msk, ws, Qb);
  k_convert_b<<<dim3(2048, 1, 1), blk, 0, stream>>>(WkP, WvP, ws);
  k_linproj<<<dim3(SP_/64,  D_/128, 4), blk, 0, stream>>>(bkP, bvP, ws, KbT, VbT, Kp, VpT);
  attn_kernel<<<dim3(512, 1, 1), dim3(512,1,1), 0, stream>>>(Qb, Kp, VpT, Xo);
  k_outproj<<<dim3(B_*S_/64, D_/128, 1), blk, 0, stream>>>(Xo, ws + WO_OFF, bo, (float*)d_out);
}

// Round 20
// 140.388 us; speedup vs baseline: 1.2359x; 1.0437x over previous
//
#include <hip/hip_runtime.h>
#include <hip/hip_bf16.h>

// Linformer MHA, MI355X gfx950. Round 20: launch consolidation — k_kv and k_q
// merged into one k_qkv launch (z in {0:K, 1:V, 2:Q}); 6 launches total.
// All kernel internals identical to round 19 (best measured).
// Pipeline (stream-ordered aliasing, ws = 32MB exactly):
//   k_convert_a: q,k,v -> Xqb[0:4M) Xkb[4M:8M) Xvb[8M:12M); Wq/Wk/Wv/Wo -> [12M:16M)
//   k_qkv  : K/V projections -> KbT/VbT in d_out; Q (masked, prescaled) -> Qb @ [4M:8M)
//   k_convert_b: WkP/WvP -> [8M:12M) (dead Xvb slot)
//   k_linproj: -> Kp[0:2M) VpT[2M:4M) (dead Xqb slot)
//   attn   : -> Xo[8M:12M)
//   k_outproj: -> fp32 d_out

typedef __attribute__((ext_vector_type(4))) float  f32x4;
typedef __attribute__((ext_vector_type(8))) short  short8;
typedef __attribute__((ext_vector_type(4))) short  short4_t;
typedef __attribute__((ext_vector_type(2))) unsigned int uint32x2;
typedef __attribute__((ext_vector_type(8))) __bf16 bf16x8;
typedef unsigned short ushort_t;

#define DEV __device__ __forceinline__

constexpr int B_ = 2, S_ = 2048, D_ = 1024, H_ = 16, SP_ = 1024;
constexpr size_t M1 = 1u << 20;
constexpr size_t XQ_OFF = 0,      XK_OFF = 4*M1,  XV_OFF = 8*M1,
                 WQ_OFF = 12*M1,  WK_OFF = 13*M1, WV_OFF = 14*M1, WO_OFF = 15*M1,
                 QB_OFF = 4*M1,   KP_OFF = 0,     VPT_OFF = 2*M1,
                 WKPB_OFF = 8*M1, WVPB_OFF = 10*M1, XO_OFF = 8*M1;
constexpr float CSC = 0.18033688011112042f;   // 0.125 * log2(e)

DEV ushort_t f2bf(float f) {              // RNE fp32 -> bf16 bits
  unsigned u = __builtin_bit_cast(unsigned, f);
  unsigned r = ((u >> 16) & 1u) + 0x7FFFu;
  return (ushort_t)((u + r) >> 16);
}
DEV bf16x8 ld8(const ushort_t* p) {
  return __builtin_bit_cast(bf16x8, *reinterpret_cast<const short8*>(p));
}
DEV f32x4 mfma16(bf16x8 a, bf16x8 b, f32x4 c) {
  return __builtin_amdgcn_mfma_f32_16x16x32_bf16(a, b, c, 0, 0, 0);
}
DEV void gload16(const ushort_t* g, ushort_t* l) {   // 16B global -> LDS direct
  __builtin_amdgcn_global_load_lds(
      (const __attribute__((address_space(1))) void*)g,
      (__attribute__((address_space(3))) void*)l, 16, 0, 0);
}
DEV void cvt2048(const float* src, ushort_t* dst, int tid) {
  const size_t off = (size_t)tid * 8;
  float4 f0 = *reinterpret_cast<const float4*>(src + off);
  float4 f1 = *reinterpret_cast<const float4*>(src + off + 4);
  ushort_t t[8] = { f2bf(f0.x), f2bf(f0.y), f2bf(f0.z), f2bf(f0.w),
                    f2bf(f1.x), f2bf(f1.y), f2bf(f1.z), f2bf(f1.w) };
  *reinterpret_cast<short8*>(dst + off) = *reinterpret_cast<short8*>(t);
}

// ---------------------------------------------------------------------------
// Conversion A: q,k,v (12M) + Wq,Wk,Wv,Wo (4M) -> bf16. 8192 blocks x 2048 el.
// ---------------------------------------------------------------------------
__global__ __launch_bounds__(256) void k_convert_a(
    const float* __restrict__ q, const float* __restrict__ k,
    const float* __restrict__ v, const float* __restrict__ Wq,
    const float* __restrict__ Wk, const float* __restrict__ Wv,
    const float* __restrict__ Wo, ushort_t* __restrict__ ws)
{
  int blk = blockIdx.x; const float* src; ushort_t* dst;
  if      (blk < 2048) { src = q;  dst = ws + XQ_OFF; }
  else if (blk < 4096) { src = k;  dst = ws + XK_OFF; blk -= 2048; }
  else if (blk < 6144) { src = v;  dst = ws + XV_OFF; blk -= 4096; }
  else if (blk < 6656) { src = Wq; dst = ws + WQ_OFF; blk -= 6144; }
  else if (blk < 7168) { src = Wk; dst = ws + WK_OFF; blk -= 6656; }
  else if (blk < 7680) { src = Wv; dst = ws + WV_OFF; blk -= 7168; }
  else                 { src = Wo; dst = ws + WO_OFF; blk -= 7680; }
  cvt2048(src + (size_t)blk * 2048, dst + (size_t)blk * 2048, threadIdx.x);
}

// Conversion B: WkP, WvP (4M elems) -> bf16. 2048 blocks.
__global__ __launch_bounds__(256) void k_convert_b(
    const float* __restrict__ WkP, const float* __restrict__ WvP,
    ushort_t* __restrict__ ws)
{
  int blk = blockIdx.x; const float* src; ushort_t* dst;
  if (blk < 1024) { src = WkP; dst = ws + WKPB_OFF; }
  else            { src = WvP; dst = ws + WVPB_OFF; blk -= 1024; }
  cvt2048(src + (size_t)blk * 2048, dst + (size_t)blk * 2048, threadIdx.x);
}

// ---------------------------------------------------------------------------
// 64x128xK bf16 MFMA GEMM, 256 thr (4 waves), BK=64, single-buffered LDS
// (24KB), 128B rows XOR-swizzled, global_load_lds both operands, XCD swizzle.
// EPI: 0 none, 1 mask-row, 2 exact-GELU, 3 mask-row + scale-by-CSC.
// OUTMODE: 0 bf16 C[m][n]; 1 fp32 C[m][n]; 2 bf16 Ct[b][n][s]; 3 bf16 Ct[n][m].
// ---------------------------------------------------------------------------
template<int BIAS, int EPI, int OUTMODE>
DEV void gemmT(const ushort_t* Ap, const ushort_t* Bp, const float* bias,
               const int* mask, void* Cp, int M, int N, int K)
{
  __shared__ __align__(16) ushort_t As[64 * 64];    // 8KB
  __shared__ __align__(16) ushort_t Bs[128 * 64];   // 16KB
  const int tid = threadIdx.x;

  const int gx = gridDim.x, gy = gridDim.y, nwg = gx * gy;
  int lin = blockIdx.y * gx + blockIdx.x;
  lin = (lin & 7) * (nwg >> 3) + (lin >> 3);
  const int m0 = (lin / gy) * 64, n0 = (lin % gy) * 128;

  const int w = tid >> 6, lane = tid & 63, lr = lane & 15, lg = lane >> 4;
  const int wm = (w >> 1) * 32, wn = (w & 1) * 64;
  const int rk7 = lr & 7;

  f32x4 acc[2][4];
#pragma unroll
  for (int i = 0; i < 2; ++i)
#pragma unroll
    for (int j = 0; j < 4; ++j) acc[i][j] = f32x4{0.f, 0.f, 0.f, 0.f};

  const int srow = tid >> 3;                          // 0..31
  const int schx = ((tid & 7) ^ (srow & 7)) * 8;      // pre-swizzled col off
  const ushort_t* Ag = Ap + (size_t)(m0 + srow) * K + schx;
  const ushort_t* Bg = Bp + (size_t)(n0 + srow) * K + schx;

  for (int k0 = 0; k0 < K; k0 += 64) {
    gload16(Ag + k0,                 As + tid*8);
    gload16(Ag + (size_t)32*K + k0,  As + 2048 + tid*8);
    gload16(Bg + k0,                 Bs + tid*8);
    gload16(Bg + (size_t)32*K + k0,  Bs + 2048 + tid*8);
    gload16(Bg + (size_t)64*K + k0,  Bs + 4096 + tid*8);
    gload16(Bg + (size_t)96*K + k0,  Bs + 6144 + tid*8);
    __syncthreads();

#pragma unroll
    for (int ks = 0; ks < 2; ++ks) {
      bf16x8 af[2], bfv[4];
#pragma unroll
      for (int i = 0; i < 2; ++i)
        af[i]  = ld8(&As[(wm + i*16 + lr)*64 + (((ks<<2)|lg) ^ rk7)*8]);
#pragma unroll
      for (int j = 0; j < 4; ++j)
        bfv[j] = ld8(&Bs[(wn + j*16 + lr)*64 + (((ks<<2)|lg) ^ rk7)*8]);
#pragma unroll
      for (int i = 0; i < 2; ++i)
#pragma unroll
        for (int j = 0; j < 4; ++j)
          acc[i][j] = mfma16(af[i], bfv[j], acc[i][j]);
    }
    __syncthreads();
  }

#pragma unroll
  for (int i = 0; i < 2; ++i) {
    const int mBase = m0 + wm + i*16 + 4*lg;
#pragma unroll
    for (int j = 0; j < 4; ++j) {
      const int n = n0 + wn + j*16 + lr;
      float vv[4];
#pragma unroll
      for (int r = 0; r < 4; ++r) {
        const int m = mBase + r;
        float v = acc[i][j][r];
        if (BIAS == 2) v += bias[n];
        if (BIAS == 1) v += bias[m];
        if (EPI == 1 || EPI == 3) v = mask[m] ? v : 0.f;
        if (EPI == 3)  v *= CSC;
        if (EPI == 2)  v = 0.5f * v * (1.f + erff(v * 0.70710678118654752f));
        vv[r] = v;
      }
      if (OUTMODE == 0) {
#pragma unroll
        for (int r = 0; r < 4; ++r)
          ((ushort_t*)Cp)[(size_t)(mBase + r) * N + n] = f2bf(vv[r]);
      } else if (OUTMODE == 1) {
#pragma unroll
        for (int r = 0; r < 4; ++r)
          ((float*)Cp)[(size_t)(mBase + r) * N + n] = vv[r];
      } else if (OUTMODE == 2) {       // Ct[b][n][s], s=m-b*S_ (K/V proj path)
        const int bb = mBase >> 11;
        const int sb = mBase & (S_ - 1);
        ushort_t t4[4] = { f2bf(vv[0]), f2bf(vv[1]), f2bf(vv[2]), f2bf(vv[3]) };
        *reinterpret_cast<short4_t*>(
            (ushort_t*)Cp + ((size_t)bb * D_ + n) * S_ + sb) =
            *reinterpret_cast<short4_t*>(t4);
      } else {                         // Ct[n][m], stride M (linproj V path)
        ushort_t t4[4] = { f2bf(vv[0]), f2bf(vv[1]), f2bf(vv[2]), f2bf(vv[3]) };
        *reinterpret_cast<short4_t*>(
            (ushort_t*)Cp + (size_t)n * M + mBase) =
            *reinterpret_cast<short4_t*>(t4);
      }
    }
  }
}

// --------------------------- kernel wrappers -------------------------------
__global__ __launch_bounds__(256) void k_qkv(
    const float* __restrict__ bq, const float* __restrict__ bk,
    const float* __restrict__ bv, const int* __restrict__ mask,
    const ushort_t* __restrict__ ws, ushort_t* __restrict__ Qb,
    ushort_t* __restrict__ KbT, ushort_t* __restrict__ VbT)
{
  if (blockIdx.z == 0)
    gemmT<2, 1, 2>(ws + XK_OFF, ws + WK_OFF, bk, mask, KbT, B_*S_, D_, D_);
  else if (blockIdx.z == 1)
    gemmT<2, 1, 2>(ws + XV_OFF, ws + WV_OFF, bv, mask, VbT, B_*S_, D_, D_);
  else
    gemmT<2, 3, 0>(ws + XQ_OFF, ws + WQ_OFF, bq, mask, Qb, B_*S_, D_, D_);
}

__global__ __launch_bounds__(256) void k_linproj(
    const float* __restrict__ bkP, const float* __restrict__ bvP,
    const ushort_t* __restrict__ ws, const ushort_t* __restrict__ KbT,
    const ushort_t* __restrict__ VbT, ushort_t* __restrict__ Kp,
    ushort_t* __restrict__ VpT)
{
  const int z = blockIdx.z, b = z >> 1, isv = z & 1;
  if (isv) {
    gemmT<1, 2, 3>(ws + WVPB_OFF, VbT + (size_t)b * D_ * S_, bvP,
                   nullptr, VpT + (size_t)b * D_ * SP_, SP_, D_, S_);
  } else {
    gemmT<1, 2, 0>(ws + WKPB_OFF, KbT + (size_t)b * D_ * S_, bkP,
                   nullptr, Kp + (size_t)b * SP_ * D_, SP_, D_, S_);
  }
}

__global__ __launch_bounds__(256) void k_outproj(
    const ushort_t* __restrict__ Xo, const ushort_t* __restrict__ Wob,
    const float* __restrict__ bo, float* __restrict__ out)
{
  gemmT<2, 0, 1>(Xo, Wob, bo, nullptr, out, B_*S_, D_, D_);
}

// ---------------------------------------------------------------------------
// Fused attention (round-19 structure, best): 512 thr, QBLK=128, KVBLK=64,
// LDS-staged K/V^T (gload, dbuf, XOR swizzle), counted-vmcnt dual-barrier
// loop, T5 setprio around compute, XCD tile remap, swapped QK^T + cvt_pk
// P-pack, prescaled-Q exp2, per-lane scalar denominator.
// ---------------------------------------------------------------------------
__global__ __launch_bounds__(512) void attn_kernel(
    const ushort_t* __restrict__ Qb, const ushort_t* __restrict__ Kp,
    const ushort_t* __restrict__ VpT, ushort_t* __restrict__ Xo)
{
  __shared__ __align__(16) ushort_t Ks[2][64 * 64];
  __shared__ __align__(16) ushort_t Vs[2][64 * 64];
  __shared__ __align__(16) ushort_t Pl[8][16][72];   // per-wave P [q][p+pad]

  // XCD tile remap: 512 tiles = 8 XCDs x 64; tile id = (lin&7)*64 + lin>>3.
  const int lin = blockIdx.x;
  const int tile = (lin & 7) * 64 + (lin >> 3);
  const int s0 = (tile & 15) * 128;          // s-fastest within (b,h)
  const int h  = (tile >> 4) & 15;
  const int b  = tile >> 8;

  const int tid = threadIdx.x, w = tid >> 6, lane = tid & 63;
  const int lr = lane & 15, lg = lane >> 4;

  const ushort_t* qp = Qb + (size_t)(b * S_ + s0 + w*16 + lr) * D_ + h * 64;
  const bf16x8 aq0 = ld8(qp + 8*lg);        // d = 0..31 slice (pre-scaled)
  const bf16x8 aq1 = ld8(qp + 32 + 8*lg);   // d = 32..63 slice

  const ushort_t* kbase = Kp  + (size_t)b * SP_ * D_ + h * 64;
  const ushort_t* vbase = VpT + (size_t)b * D_ * SP_ + (size_t)(h*64) * SP_;

  const int srow = tid >> 3, sch = tid & 7;
  const int schx = (sch ^ (srow & 7)) << 3;
  const int rk7 = lr & 7;

  f32x4 o[4];
#pragma unroll
  for (int dt = 0; dt < 4; ++dt) o[dt] = f32x4{0.f, 0.f, 0.f, 0.f};
  float lsum4[4] = {0.f, 0.f, 0.f, 0.f};    // per-lane (q=lr) partial denoms

  auto stage = [&](int buf, int p0) {
    gload16(kbase + (size_t)(p0 + srow) * D_ + schx, Ks[buf] + tid*8);
    gload16(vbase + (size_t)srow * SP_ + p0 + schx,  Vs[buf] + tid*8);
  };

  stage(0, 0);
  int cur = 0;
  for (int pt = 0; pt < SP_ / 64; ++pt) {
    if (pt + 1 < SP_ / 64) {
      stage(cur ^ 1, (pt + 1) * 64);
      asm volatile("s_waitcnt vmcnt(2)" ::: "memory");  // cur's 2 loads done
    } else {
      asm volatile("s_waitcnt vmcnt(0)" ::: "memory");
    }
    __builtin_amdgcn_s_barrier();
    __builtin_amdgcn_sched_barrier(0);
    __builtin_amdgcn_s_setprio(1);

    // ---- S^T = K Q^T (swapped); P = exp2(S^T); pack + 1 b64 write/nt ----
#pragma unroll
    for (int nt = 0; nt < 4; ++nt) {
      const ushort_t* krow = Ks[cur] + (nt*16 + lr) * 64;
      f32x4 a = f32x4{0.f, 0.f, 0.f, 0.f};
      a = mfma16(ld8(krow + ((lg       ^ rk7) << 3)), aq0, a);
      a = mfma16(ld8(krow + (((4 + lg) ^ rk7) << 3)), aq1, a);
      const float e0 = __builtin_exp2f(a[0]);
      const float e1 = __builtin_exp2f(a[1]);
      const float e2 = __builtin_exp2f(a[2]);
      const float e3 = __builtin_exp2f(a[3]);
      lsum4[nt] += (e0 + e1) + (e2 + e3);
      unsigned p01, p23;
      asm("v_cvt_pk_bf16_f32 %0, %1, %2" : "=v"(p01) : "v"(e0), "v"(e1));
      asm("v_cvt_pk_bf16_f32 %0, %1, %2" : "=v"(p23) : "v"(e2), "v"(e3));
      uint32x2 pw; pw[0] = p01; pw[1] = p23;
      *reinterpret_cast<uint32x2*>(&Pl[w][lr][nt*16 + 4*lg]) = pw;
    }

    // ---- O += P @ V ----
    const bf16x8 pa0 = ld8(&Pl[w][lr][8*lg]);        // p = 0..31 slice
    const bf16x8 pa1 = ld8(&Pl[w][lr][32 + 8*lg]);   // p = 32..63 slice
#pragma unroll
    for (int dt = 0; dt < 4; ++dt) {
      const ushort_t* vrow = Vs[cur] + (dt*16 + lr) * 64;
      o[dt] = mfma16(pa0, ld8(vrow + ((lg       ^ rk7) << 3)), o[dt]);
      o[dt] = mfma16(pa1, ld8(vrow + (((4 + lg) ^ rk7) << 3)), o[dt]);
    }

    __builtin_amdgcn_s_setprio(0);
    __builtin_amdgcn_sched_barrier(0);
    __builtin_amdgcn_s_barrier();
    cur ^= 1;
  }

  // ---- denominator: reduce 4 lane-groups (same q=lr), then broadcast ----
  float lsum = (lsum4[0] + lsum4[1]) + (lsum4[2] + lsum4[3]);
  lsum += __shfl_xor(lsum, 16, 64);
  lsum += __shfl_xor(lsum, 32, 64);          // every lane: total for q=lr
  float linv[4];
#pragma unroll
  for (int r = 0; r < 4; ++r)
    linv[r] = 1.f / __shfl(lsum, 4*lg + r, 64);   // lane (4lg+r) has q=4lg+r

#pragma unroll
  for (int dt = 0; dt < 4; ++dt)
#pragma unroll
    for (int r = 0; r < 4; ++r) {
      const int srow2 = s0 + w*16 + 4*lg + r;
      Xo[(size_t)(b * S_ + srow2) * D_ + h*64 + dt*16 + lr] =
          f2bf(o[dt][r] * linv[r]);
    }
}

// ------------------------------- launch ------------------------------------
extern "C" void kernel_launch(void* const* d_in, const int* in_sizes, int n_in,
                              void* d_out, int out_size, void* d_ws, size_t ws_size,
                              hipStream_t stream)
{
  const float* q   = (const float*)d_in[0];
  const float* k   = (const float*)d_in[1];
  const float* v   = (const float*)d_in[2];
  const int*   msk = (const int*)d_in[3];
  const float* Wq  = (const float*)d_in[4];
  const float* bq  = (const float*)d_in[5];
  const float* Wk  = (const float*)d_in[6];
  const float* bk  = (const float*)d_in[7];
  const float* Wv  = (const float*)d_in[8];
  const float* bv  = (const float*)d_in[9];
  const float* Wo  = (const float*)d_in[10];
  const float* bo  = (const float*)d_in[11];
  const float* WkP = (const float*)d_in[12];
  const float* bkP = (const float*)d_in[13];
  const float* WvP = (const float*)d_in[14];
  const float* bvP = (const float*)d_in[15];

  ushort_t* ws  = (ushort_t*)d_ws;
  ushort_t* Qb  = ws + QB_OFF;
  ushort_t* Kp  = ws + KP_OFF;
  ushort_t* VpT = ws + VPT_OFF;
  ushort_t* Xo  = ws + XO_OFF;
  ushort_t* KbT = (ushort_t*)d_out;     // d_out as scratch until k_outproj
  ushort_t* VbT = KbT + 4 * M1;

  dim3 blk(256, 1, 1);
  k_convert_a<<<dim3(8192, 1, 1), blk, 0, stream>>>(q, k, v, Wq, Wk, Wv, Wo, ws);
  k_qkv    <<<dim3(B_*S_/64, D_/128, 3), blk, 0, stream>>>(bq, bk, bv, msk, ws, Qb, KbT, VbT);
  k_convert_b<<<dim3(2048, 1, 1), blk, 0, stream>>>(WkP, WvP, ws);
  k_linproj<<<dim3(SP_/64,  D_/128, 4), blk, 0, stream>>>(bkP, bvP, ws, KbT, VbT, Kp, VpT);
  attn_kernel<<<dim3(512, 1, 1), dim3(512,1,1), 0, stream>>>(Qb, Kp, VpT, Xo);
  k_outproj<<<dim3(B_*S_/64, D_/128, 1), blk, 0, stream>>>(Xo, ws + WO_OFF, bo, (float*)d_out);
}